// Round 14
// baseline (1849.690 us; speedup 1.0000x reference)
//
#include <hip/hip_runtime.h>
#include <stdint.h>

// Problem constants (B=4,S=1024,D=1024,N=32768,n_chunks=8)
#define M_TOT 4096
#define D_DIM 1024
#define N_NEUR 32768
#define NCHUNK 8
#define CS 4096

typedef float f32x4 __attribute__((ext_vector_type(4)));
typedef __bf16 bf16x8 __attribute__((ext_vector_type(8)));
typedef unsigned short u16;
typedef unsigned int u32;
typedef u16 u16x8 __attribute__((ext_vector_type(8)));
typedef u16 u16x4 __attribute__((ext_vector_type(4)));

__device__ __forceinline__ u16 f2bf(float f) {
    u32 u = __builtin_bit_cast(u32, f);
    u = (u + 0x7FFFu + ((u >> 16) & 1u)) >> 16;
    return (u16)u;
}
__device__ __forceinline__ float bf2f(u16 h) {
    u32 u = ((u32)h) << 16;
    return __builtin_bit_cast(float, u);
}
__device__ __forceinline__ u32 pack2(float a, float b, float s) {
    return (u32)f2bf(a * s) | ((u32)f2bf(b * s) << 16);
}

typedef __attribute__((address_space(1))) const u32 as1_u32;
typedef __attribute__((address_space(3))) u32 as3_u32;
__device__ __forceinline__ void gload16(const void* g, void* l) {
    __builtin_amdgcn_global_load_lds((as1_u32*)g, (as3_u32*)l, 16, 0, 0);
}

#define MFMA(a, b, c) __builtin_amdgcn_mfma_f32_16x16x32_bf16((a), (b), (c), 0, 0, 0)

// XCD-aware block swizzle for grid (32,256): XCD k (linear id % 8) owns
// bn in [k*32,(k+1)*32) so the shared 128-row B panel stays in one L2.
// Bijective: L -> (L&7, L>>3) -> (bn,bm) covers all 8192 pairs once.
#define XCD_SWIZZLE_BMBN()                                                            \
    int bm, bn;                                                                       \
    if (gridDim.y == 256) {                                                           \
        int L = blockIdx.x + (blockIdx.y << 5);                                       \
        int j = L >> 3;                                                               \
        bn = ((L & 7) << 5) + (j >> 5);                                               \
        bm = j & 31;                                                                  \
    } else {                                                                          \
        bm = blockIdx.x;                                                              \
        bn = blockIdx.y;                                                              \
    }

// 128x128-tile bf16 GEMM main loop (m97 structure: BK=32, linear LDS,
// global_load_lds width-16, 2 barriers/K-step). Separate A/B row strides.
// LDS[17408] u16 (34 KB): GEMM uses first 8192; the epilogue restage uses the
// full array as 128 rows x stride 136 (max idx 127*136+127 = 17399 < 17408).
#define GEMM128_BODY(ABASE, ASTR, BBASE, BSTR, KLEN)                                  \
    __shared__ u16 LDS[17408];                                                        \
    u16* Al = LDS;                                                                    \
    u16* Bl = LDS + 4096;                                                             \
    const int t = threadIdx.x, lane = t & 63, w = t >> 6;                             \
    const int wr = w >> 1, wc = w & 1, l15 = lane & 15, lg = lane >> 4;               \
    f32x4 acc[4][4] = {};                                                             \
    {                                                                                 \
        const int rb = lane >> 2, cl = (lane & 3) * 8;                                \
        const int seg0 = w * 2;                                                       \
        const size_t ro0 = (size_t)(seg0 * 16 + rb);                                  \
        const u16* pa0 = (ABASE) + ((size_t)bm * 128 + ro0) * (ASTR) + cl;            \
        const u16* pb0 = (BBASE) + ((size_t)bn * 128 + ro0) * (BSTR) + cl;            \
        const u16* pa1 = pa0 + (size_t)16 * (ASTR);                                   \
        const u16* pb1 = pb0 + (size_t)16 * (BSTR);                                   \
        u16* la0 = Al + seg0 * 512;                                                   \
        u16* lb0 = Bl + seg0 * 512;                                                   \
        for (int k0 = 0; k0 < (KLEN); k0 += 32) {                                     \
            __syncthreads();                                                          \
            gload16(pa0 + k0, la0);                                                   \
            gload16(pa1 + k0, la0 + 512);                                             \
            gload16(pb0 + k0, lb0);                                                   \
            gload16(pb1 + k0, lb0 + 512);                                             \
            __syncthreads();                                                          \
            bf16x8 afr[4], bfr[4];                                                    \
            _Pragma("unroll") for (int m = 0; m < 4; m++)                             \
                afr[m] = *(const bf16x8*)&Al[(wr * 64 + m * 16 + l15) * 32 + lg * 8]; \
            _Pragma("unroll") for (int n = 0; n < 4; n++)                             \
                bfr[n] = *(const bf16x8*)&Bl[(wc * 64 + n * 16 + l15) * 32 + lg * 8]; \
            _Pragma("unroll") for (int m = 0; m < 4; m++)                             \
                _Pragma("unroll") for (int n = 0; n < 4; n++)                         \
                    acc[m][n] = MFMA(afr[m], bfr[n], acc[m][n]);                      \
        }                                                                             \
    }

// Single-pass full-tile restage: fragments -> LDS[128 rows][stride 136].
#define RESTAGE_TO_LDS(VALS)                                                          \
    __syncthreads();                                                                  \
    _Pragma("unroll") for (int m = 0; m < 4; m++)                                     \
        _Pragma("unroll") for (int rr = 0; rr < 4; rr++)                              \
            _Pragma("unroll") for (int n = 0; n < 4; n++) {                           \
                int lrow = wr * 64 + m * 16 + lg * 4 + rr;                            \
                LDS[lrow * 136 + wc * 64 + n * 16 + l15] = (VALS);                    \
            }                                                                         \
    __syncthreads();

// Full-tile row-major u16 writeout via the single restage (two read passes).
#define RESTAGE_U16_TILE(VALS, DSTBASE, DSTSTRIDE, COLBASE)                           \
    {                                                                                 \
        RESTAGE_TO_LDS(VALS)                                                          \
        int row_ = t >> 2, c0_ = (t & 3) * 32;                                        \
        _Pragma("unroll") for (int p = 0; p < 2; p++) {                               \
            int lrow = p * 64 + row_;                                                 \
            u16* dst_ = (DSTBASE) + (size_t)(bm * 128 + lrow) * (DSTSTRIDE) +         \
                        (COLBASE) + c0_;                                              \
            const u16* srcl_ = &LDS[lrow * 136 + c0_];                                \
            _Pragma("unroll") for (int j = 0; j < 4; j++)                             \
                *(u16x8*)(dst_ + j * 8) = *(const u16x8*)(srcl_ + j * 8);             \
        }                                                                             \
    }

// ---------------- prep: h,x -> bf16 ----------------------------------------
__global__ __launch_bounds__(256) void k_cvt(const float* __restrict__ h,
                                             const float* __restrict__ x,
                                             u16* __restrict__ hb, u16* __restrict__ xb) {
    size_t i = ((size_t)blockIdx.x * 256 + threadIdx.x) * 4;
    float4 v = *(const float4*)(h + i);
    uint2 o;
    o.x = pack2(v.x, v.y, 1.0f);
    o.y = pack2(v.z, v.w, 1.0f);
    *(uint2*)(hb + i) = o;
    v = *(const float4*)(x + i);
    o.x = pack2(v.x, v.y, 1.0f);
    o.y = pack2(v.z, v.w, 1.0f);
    *(uint2*)(xb + i) = o;
}

// ---------------- fused norm+convert: y=0 emb->ebf, y=1 w_read->rbf, y=2 sw --
__global__ __launch_bounds__(256) void k_cvt_ern3(const float* __restrict__ emb,
                                                  const float* __restrict__ wrd,
                                                  const float* __restrict__ ww,
                                                  u16* __restrict__ ebf, u16* __restrict__ rbf,
                                                  float* __restrict__ sw) {
    int t = threadIdx.x, lane = t & 63, wv = t >> 6;
    int row = blockIdx.x * 4 + wv;
    int which = blockIdx.y;
    const float* srcm = which == 0 ? emb : (which == 1 ? wrd : ww);
    const float4* src = (const float4*)(srcm + (size_t)row * D_DIM);
    float4 v[4];
    float ss = 0.f;
#pragma unroll
    for (int j = 0; j < 4; j++) {
        v[j] = src[j * 64 + lane];
        if (which == 0) {
            ss += v[j].x * v[j].x + v[j].y * v[j].y + v[j].z * v[j].z + v[j].w * v[j].w;
        } else {
            float a = bf2f(f2bf(v[j].x)), b = bf2f(f2bf(v[j].y));
            float c = bf2f(f2bf(v[j].z)), d = bf2f(f2bf(v[j].w));
            ss += a * a + b * b + c * c + d * d;
        }
    }
#pragma unroll
    for (int s = 1; s < 64; s <<= 1) ss += __shfl_xor(ss, s);
    float sc = 1.0f / (sqrtf(ss) + 1e-8f);
    if (which == 2) {
        if (lane == 0) sw[row] = sc;
        return;
    }
    uint2* dst = (uint2*)((which == 0 ? ebf : rbf) + (size_t)row * D_DIM);
#pragma unroll
    for (int j = 0; j < 4; j++) {
        uint2 o;
        o.x = pack2(v[j].x, v[j].y, sc);
        o.y = pack2(v[j].z, v[j].w, sc);
        dst[j * 64 + lane] = o;
    }
}

// per-chunk variants for the compact fallback path
__global__ __launch_bounds__(256) void k_cvt_e_norm(const float* __restrict__ emb,
                                                    int cbase, u16* __restrict__ ebf) {
    int t = threadIdx.x, lane = t & 63, wv = t >> 6;
    int row = blockIdx.x * 4 + wv;
    const float4* src = (const float4*)(emb + (size_t)(cbase + row) * D_DIM);
    float4 v[4];
    float ss = 0.f;
#pragma unroll
    for (int j = 0; j < 4; j++) {
        v[j] = src[j * 64 + lane];
        ss += v[j].x * v[j].x + v[j].y * v[j].y + v[j].z * v[j].z + v[j].w * v[j].w;
    }
#pragma unroll
    for (int s = 1; s < 64; s <<= 1) ss += __shfl_xor(ss, s);
    float es = 1.0f / (sqrtf(ss) + 1e-8f);
    uint2* dst = (uint2*)(ebf + (size_t)row * D_DIM);
#pragma unroll
    for (int j = 0; j < 4; j++) {
        uint2 o;
        o.x = pack2(v[j].x, v[j].y, es);
        o.y = pack2(v[j].z, v[j].w, es);
        dst[j * 64 + lane] = o;
    }
}

__global__ __launch_bounds__(256) void k_cvt_r_norm(const float* __restrict__ wrd,
                                                    int cbase, u16* __restrict__ rbf) {
    int t = threadIdx.x, lane = t & 63, wv = t >> 6;
    int row = blockIdx.x * 4 + wv;
    const float4* src = (const float4*)(wrd + (size_t)(cbase + row) * D_DIM);
    float4 v[4];
    float ss = 0.f;
#pragma unroll
    for (int j = 0; j < 4; j++) {
        v[j] = src[j * 64 + lane];
        float a = bf2f(f2bf(v[j].x)), b = bf2f(f2bf(v[j].y));
        float c = bf2f(f2bf(v[j].z)), d = bf2f(f2bf(v[j].w));
        ss += a * a + b * b + c * c + d * d;
    }
#pragma unroll
    for (int s = 1; s < 64; s <<= 1) ss += __shfl_xor(ss, s);
    float rs = 1.0f / (sqrtf(ss) + 1e-8f);
    uint2* dst = (uint2*)(rbf + (size_t)row * D_DIM);
#pragma unroll
    for (int j = 0; j < 4; j++) {
        uint2 o;
        o.x = pack2(v[j].x, v[j].y, rs);
        o.y = pack2(v[j].z, v[j].w, rs);
        dst[j * 64 + lane] = o;
    }
}

// ---------------- w_write row norms (fallback path) ---------------------------
__global__ __launch_bounds__(256) void k_sw(const float* __restrict__ ww, float* sw) {
    int t = threadIdx.x, lane = t & 63, wv = t >> 6;
    int row = blockIdx.x * 4 + wv;
    const float4* src = (const float4*)(ww + (size_t)row * D_DIM);
    float ss = 0.f;
#pragma unroll
    for (int j = 0; j < 4; j++) {
        float4 v = src[j * 64 + lane];
        float a = bf2f(f2bf(v.x)), b = bf2f(f2bf(v.y));
        float c = bf2f(f2bf(v.z)), d = bf2f(f2bf(v.w));
        ss += a * a + b * b + c * c + d * d;
    }
#pragma unroll
    for (int s = 1; s < 64; s <<= 1) ss += __shfl_xor(ss, s);
    if (lane == 0) sw[row] = 1.0f / (sqrtf(ss) + 1e-8f);
}

// ---------------- transpose w_write -> wwT[d][k] bf16 ------------------------
__global__ __launch_bounds__(256) void k_tww(const float* __restrict__ ww,
                                             const float* __restrict__ sw,
                                             int cbase, u16* __restrict__ wwT, int dstr) {
    __shared__ u16 tile[64][80];
    int kt = blockIdx.x * 64;
    int dt = blockIdx.y * 64;
    int t = threadIdx.x;
    int kk = t >> 4;
    int dd = (t & 15) * 4;
#pragma unroll
    for (int i = 0; i < 4; i++) {
        int krow = kk + i * 16;
        int kg = cbase + kt + krow;
        float s = sw[kg];
        float4 v = *(const float4*)(ww + (size_t)kg * D_DIM + dt + dd);
        tile[dd + 0][krow] = f2bf(v.x * s);
        tile[dd + 1][krow] = f2bf(v.y * s);
        tile[dd + 2][krow] = f2bf(v.z * s);
        tile[dd + 3][krow] = f2bf(v.w * s);
    }
    __syncthreads();
    int dd2 = t >> 2;
    int kk2 = (t & 3) * 16;
    uint4 o0 = *(const uint4*)&tile[dd2][kk2];
    uint4 o1 = *(const uint4*)&tile[dd2][kk2 + 8];
    u16* dst = wwT + (size_t)(dt + dd2) * dstr + kt + kk2;
    *(uint4*)dst = o0;
    *(uint4*)(dst + 8) = o1;
}

// ---------------- pass 1: scores GEMM + stats + row-major sb ------------------
__global__ __launch_bounds__(256) void k_pass1(const u16* __restrict__ hb,
                                               const u16* __restrict__ ebf, int cbase,
                                               float* rowsum, float* rowsq, float* colsum,
                                               u16* __restrict__ sb, int sstr) {
    XCD_SWIZZLE_BMBN()
    GEMM128_BODY(hb, D_DIM, ebf, D_DIM, D_DIM)
    // column sums from fragments (bf16-rounded values)
    float csv[4] = {0.f, 0.f, 0.f, 0.f};
#pragma unroll
    for (int m = 0; m < 4; m++)
#pragma unroll
        for (int rr = 0; rr < 4; rr++)
#pragma unroll
            for (int n = 0; n < 4; n++) csv[n] += bf2f(f2bf(acc[m][n][rr]));
#pragma unroll
    for (int n = 0; n < 4; n++) {
        float cv = csv[n];
        cv += __shfl_xor(cv, 16);
        cv += __shfl_xor(cv, 32);
        if (lg == 0) {
            int ng = cbase + bn * 128 + wc * 64 + n * 16 + l15;
            atomicAdd(&colsum[ng], cv);
        }
    }
    // restage full tile once; row stats + coalesced sb store in two passes
    RESTAGE_TO_LDS(f2bf(acc[m][n][rr]))
    int row_ = t >> 2, c0_ = (t & 3) * 32;
#pragma unroll
    for (int p = 0; p < 2; p++) {
        int lrow = p * 64 + row_;
        int grow = bm * 128 + lrow;
        float rs = 0.f, rq = 0.f;
        u16* dst = sb ? (sb + (size_t)grow * sstr + cbase + bn * 128 + c0_) : (u16*)nullptr;
#pragma unroll
        for (int j = 0; j < 4; j++) {
            u16x8 v = *(const u16x8*)&LDS[lrow * 136 + c0_ + j * 8];
            if (dst) *(u16x8*)(dst + j * 8) = v;
#pragma unroll
            for (int q = 0; q < 8; q++) {
                float sv = bf2f(v[q]);
                rs += sv;
                rq += sv * sv;
            }
        }
        rs += __shfl_xor(rs, 1);
        rq += __shfl_xor(rq, 1);
        rs += __shfl_xor(rs, 2);
        rq += __shfl_xor(rq, 2);
        if ((lane & 3) == 0) {
            atomicAdd(&rowsum[grow], rs);
            atomicAdd(&rowsq[grow], rq);
        }
    }
}

// ---------------- ns stats reduce -------------------------------------------
__global__ __launch_bounds__(256) void k_ns(const float* __restrict__ colsum, float* scal) {
    int i = blockIdx.x * 256 + threadIdx.x;
    float pm = colsum[i] * (1.0f / 4096.0f);
    float s1 = pm, s2 = pm * pm;
#pragma unroll
    for (int x = 1; x < 64; x <<= 1) {
        s1 += __shfl_xor(s1, x);
        s2 += __shfl_xor(s2, x);
    }
    __shared__ float sh[2][4];
    int w = threadIdx.x >> 6;
    if ((threadIdx.x & 63) == 0) { sh[0][w] = s1; sh[1][w] = s2; }
    __syncthreads();
    if (threadIdx.x == 0) {
        atomicAdd(&scal[0], sh[0][0] + sh[0][1] + sh[0][2] + sh[0][3]);
        atomicAdd(&scal[1], sh[1][0] + sh[1][1] + sh[1][2] + sh[1][3]);
    }
}

// ---------------- tau --------------------------------------------------------
__global__ __launch_bounds__(256) void k_tau(const float* __restrict__ rowsum,
                                             const float* __restrict__ rowsq,
                                             const float* __restrict__ tau_off,
                                             float* tau, float* invstd, float* smean, float* sstd) {
    int i = blockIdx.x * 256 + threadIdx.x;
    float sm = rowsum[i] * (1.0f / 32768.0f);
    float var = rowsq[i] * (1.0f / 32768.0f) - sm * sm;
    float sd = sqrtf(var) + 1e-8f;
    smean[i] = sm;
    sstd[i] = sd;
    invstd[i] = 1.0f / sd;
    tau[i] = sm + tau_off[i] * sd;
}

// ---------------- flow A: xr GEMM + gate, P in-place into sb ------------------
__global__ __launch_bounds__(256) void k_xr_gate_all(const u16* __restrict__ xb,
                                                     const u16* __restrict__ rbf,
                                                     u16* __restrict__ sbP,
                                                     const float* __restrict__ tau,
                                                     const float* __restrict__ invstd,
                                                     float* twc, float* act) {
    XCD_SWIZZLE_BMBN()
    const int tt = threadIdx.x;
    const int prow = tt >> 2, pc0 = (tt & 3) * 32;
    u16x8 sv_pre[2][4];
#pragma unroll
    for (int p = 0; p < 2; p++) {
        int grow = bm * 128 + p * 64 + prow;
        const u16* src = sbP + (size_t)grow * N_NEUR + bn * 128 + pc0;
#pragma unroll
        for (int j = 0; j < 4; j++) sv_pre[p][j] = *(const u16x8*)(src + j * 8);
    }
    GEMM128_BODY(xb, D_DIM, rbf, D_DIM, D_DIM)
    RESTAGE_TO_LDS(f2bf(acc[m][n][rr]))
#pragma unroll
    for (int p = 0; p < 2; p++) {
        int lrow = p * 64 + prow;
        int grow = bm * 128 + lrow;
        float tl = tau[grow], il = invstd[grow];
        float wsum = 0.f, cnt = 0.f;
        u16* gptr = sbP + (size_t)grow * N_NEUR + bn * 128 + pc0;
#pragma unroll
        for (int j = 0; j < 4; j++) {
            u16x8 xr8 = *(const u16x8*)&LDS[lrow * 136 + pc0 + j * 8];
            u16x8 sv8 = sv_pre[p][j];
            u16x8 o;
#pragma unroll
            for (int q = 0; q < 8; q++) {
                float xf = bf2f(xr8[q]);
                float raw = bf2f(sv8[q]) - tl;
                float sig = 1.0f / (1.0f + __expf(-raw * il));
                bool g = raw > 0.0f;
                wsum += sig * xf * xf;
                cnt += g ? 1.0f : 0.0f;
                o[q] = g ? xr8[q] : (u16)0;
            }
            *(u16x8*)(gptr + j * 8) = o;
        }
        wsum += __shfl_xor(wsum, 1);
        cnt += __shfl_xor(cnt, 1);
        wsum += __shfl_xor(wsum, 2);
        cnt += __shfl_xor(cnt, 2);
        if ((lane & 3) == 0) {
            atomicAdd(&twc[grow], wsum);
            atomicAdd(&act[grow], cnt);
        }
    }
}

// ---------------- flow A: all-chunk write GEMM -> bf16 partials --------------
__global__ __launch_bounds__(256) void k_pass2b_all(const u16* __restrict__ sbP,
                                                    const u16* __restrict__ wwT,
                                                    u16* __restrict__ part) {
    int bm = blockIdx.x;
    int bn = blockIdx.y;
    int zz = blockIdx.z;
    const u16* Pz = sbP + (size_t)zz * CS;
    const u16* Wz = wwT + (size_t)zz * CS;
    u16* pz = part + (size_t)zz * M_TOT * D_DIM;
    GEMM128_BODY(Pz, N_NEUR, Wz, N_NEUR, CS)
    RESTAGE_U16_TILE(f2bf(acc[m][n][rr]), pz, D_DIM, bn * 128)
}

// ---------------- final: sum bf16 partials, normalize, per-row outputs -------
__global__ __launch_bounds__(256) void k_norm_comb(const u16* __restrict__ part,
                                                   const float* __restrict__ twc,
                                                   const float* __restrict__ act,
                                                   float* __restrict__ out0,
                                                   float* out1, float* out2) {
    int row = blockIdx.x;
    float den = sqrtf(twc[row] + 1e-6f);
    den = fmaxf(den, 0.001f);
    float inv = 1.0f / den;
    size_t base = (size_t)row * D_DIM + threadIdx.x * 4;
    float s0 = 0.f, s1 = 0.f, s2 = 0.f, s3 = 0.f;
#pragma unroll
    for (int c = 0; c < NCHUNK; c++) {
        u16x4 v = *(const u16x4*)(part + (size_t)c * M_TOT * D_DIM + base);
        s0 += bf2f(v[0]);
        s1 += bf2f(v[1]);
        s2 += bf2f(v[2]);
        s3 += bf2f(v[3]);
    }
    float4 o;
    o.x = bf2f(f2bf(s0 * inv));
    o.y = bf2f(f2bf(s1 * inv));
    o.z = bf2f(f2bf(s2 * inv));
    o.w = bf2f(f2bf(s3 * inv));
    *(float4*)(out0 + base) = o;
    if (threadIdx.x == 0) {
        out1[row] = act[row] * (1.0f / 32768.0f);
        out2[row] = act[row] > 0.0f ? 1.0f : 0.0f;
    }
}

// ---------------- flow B kernels (compact fallback) ---------------------------
__global__ __launch_bounds__(256) void k_xr_plain(const u16* __restrict__ xb,
                                                  const u16* __restrict__ rbf,
                                                  u16* __restrict__ P) {
    int bm = blockIdx.x, bn = blockIdx.y;
    GEMM128_BODY(xb, D_DIM, rbf, D_DIM, D_DIM)
    RESTAGE_U16_TILE(f2bf(acc[m][n][rr]), P, CS, bn * 128)
}

__global__ __launch_bounds__(256) void k_gate_gemm(const u16* __restrict__ hb,
                                                   const u16* __restrict__ ebf,
                                                   const float* __restrict__ tau,
                                                   const float* __restrict__ invstd,
                                                   u16* __restrict__ P, float* twc, float* act) {
    int bm = blockIdx.x, bn = blockIdx.y;
    GEMM128_BODY(hb, D_DIM, ebf, D_DIM, D_DIM)
#pragma unroll
    for (int m = 0; m < 4; m++) {
#pragma unroll
        for (int rr = 0; rr < 4; rr++) {
            int mg = bm * 128 + wr * 64 + m * 16 + lg * 4 + rr;
            float tl = tau[mg], il = invstd[mg];
            float wsum = 0.f, cnt = 0.f;
#pragma unroll
            for (int n = 0; n < 4; n++) {
                int ngl = bn * 128 + wc * 64 + n * 16 + l15;
                float sv = bf2f(f2bf(acc[m][n][rr]));
                float raw = sv - tl;
                u16 xrb = P[(size_t)mg * CS + ngl];
                float xf = bf2f(xrb);
                float sig = 1.0f / (1.0f + __expf(-raw * il));
                bool g = raw > 0.0f;
                wsum += sig * xf * xf;
                cnt += g ? 1.0f : 0.0f;
                P[(size_t)mg * CS + ngl] = g ? xrb : (u16)0;
            }
#pragma unroll
            for (int x = 1; x < 16; x <<= 1) {
                wsum += __shfl_xor(wsum, x);
                cnt += __shfl_xor(cnt, x);
            }
            if (l15 == 0) {
                atomicAdd(&twc[mg], wsum);
                atomicAdd(&act[mg], cnt);
            }
        }
    }
}

__global__ __launch_bounds__(256) void k_pass2b(const u16* __restrict__ P,
                                                const u16* __restrict__ wwT, int bstr,
                                                float* __restrict__ out) {
    int bm = blockIdx.x;
    int bn = blockIdx.y;
    GEMM128_BODY(P, CS, wwT, bstr, CS)
#pragma unroll
    for (int m = 0; m < 4; m++)
#pragma unroll
        for (int n = 0; n < 4; n++)
#pragma unroll
            for (int rr = 0; rr < 4; rr++) {
                int mg = bm * 128 + wr * 64 + m * 16 + lg * 4 + rr;
                int dg = bn * 128 + wc * 64 + n * 16 + l15;
                out[(size_t)mg * D_DIM + dg] += bf2f(f2bf(acc[m][n][rr]));
            }
}

__global__ __launch_bounds__(256) void k_norm_f(float* __restrict__ out,
                                                const float* __restrict__ twc,
                                                const float* __restrict__ act,
                                                float* out1, float* out2) {
    int row = blockIdx.x;
    float den = sqrtf(twc[row] + 1e-6f);
    den = fmaxf(den, 0.001f);
    float inv = 1.0f / den;
    float* p = out + (size_t)row * D_DIM;
    int i = threadIdx.x * 4;
    float4 v = *(float4*)(p + i);
    v.x = bf2f(f2bf(v.x * inv));
    v.y = bf2f(f2bf(v.y * inv));
    v.z = bf2f(f2bf(v.z * inv));
    v.w = bf2f(f2bf(v.w * inv));
    *(float4*)(p + i) = v;
    if (threadIdx.x == 0) {
        out1[row] = act[row] * (1.0f / 32768.0f);
        out2[row] = act[row] > 0.0f ? 1.0f : 0.0f;
    }
}

// ---------------- scalar outputs ---------------------------------------------
__global__ __launch_bounds__(256) void k_scalars(const float* __restrict__ smean,
                                                 const float* __restrict__ sstd,
                                                 const float* __restrict__ twc,
                                                 const float* __restrict__ act,
                                                 const float* __restrict__ scal,
                                                 float* outS) {
    float a = 0.f, b = 0.f, c = 0.f, d = 0.f;
    for (int i = threadIdx.x; i < 4096; i += 256) {
        a += smean[i];
        b += sstd[i];
        c += twc[i];
        d += act[i];
    }
#pragma unroll
    for (int x = 1; x < 64; x <<= 1) {
        a += __shfl_xor(a, x);
        b += __shfl_xor(b, x);
        c += __shfl_xor(c, x);
        d += __shfl_xor(d, x);
    }
    __shared__ float sh[4][4];
    int w = threadIdx.x >> 6;
    if ((threadIdx.x & 63) == 0) { sh[0][w] = a; sh[1][w] = b; sh[2][w] = c; sh[3][w] = d; }
    __syncthreads();
    if (threadIdx.x == 0) {
        float ma = sh[0][0] + sh[0][1] + sh[0][2] + sh[0][3];
        float mb = sh[1][0] + sh[1][1] + sh[1][2] + sh[1][3];
        float mc = sh[2][0] + sh[2][1] + sh[2][2] + sh[2][3];
        float md = sh[3][0] + sh[3][1] + sh[3][2] + sh[3][3];
        float mean_score = scal[0] * (1.0f / 32768.0f);
        float var_score = scal[1] * (1.0f / 32768.0f) - mean_score * mean_score;
        outS[0] = var_score / (mean_score * mean_score + var_score + 0.01f);  // score_lb
        outS[1] = mb * (1.0f / 4096.0f);                                      // score_std_out
        outS[2] = mc * (1.0f / 4096.0f);                                      // es_out
        outS[3] = md * (1.0f / 4096.0f);                                      // active_n_mean
        outS[4] = ma * (1.0f / 4096.0f);                                      // score_mean_out
    }
}

// ---------------- workspace layout (bytes) -----------------------------------
static constexpr size_t OFF_HB     = 0;           // 8 MB
static constexpr size_t OFF_XB     = 8388608;     // 8 MB
static constexpr size_t OFF_P      = 16777216;    // 32 MB (fallback only)
static constexpr size_t OFF_EBF    = 50331648;    // 64 MB; part (64 MB bf16) overlays
static constexpr size_t OFF_RBF    = 117440512;   // 64 MB
static constexpr size_t OFF_WWT    = 184549376;   // 64 MB  [D][N] (flow A) / [D][CS] fallback
static constexpr size_t OFF_SW     = 251658240;   // 128 KB
static constexpr size_t OFF_ROWSUM = 251789312;
static constexpr size_t OFF_ROWSQ  = 251805696;
static constexpr size_t OFF_COLSUM = 251822080;   // 128 KB
static constexpr size_t OFF_TAU    = 251953152;
static constexpr size_t OFF_INVSTD = 251969536;
static constexpr size_t OFF_SMEAN  = 251985920;
static constexpr size_t OFF_SSTD   = 252002304;
static constexpr size_t OFF_TWC    = 252018688;
static constexpr size_t OFF_ACT    = 252035072;
static constexpr size_t OFF_SCAL   = 252051456;
static constexpr size_t STATS_END  = 252051520;
static constexpr size_t ZERO_LEN   = STATS_END - OFF_ROWSUM;
static constexpr size_t OFF_SB     = 252706816;   // 256 MB (flow A) scores -> gated P
static constexpr size_t FULL_END   = OFF_SB + (size_t)M_TOT * N_NEUR * 2;  // ~497 MB
static constexpr size_t OFF_PART   = OFF_EBF;     // 64 MB bf16 partials overlay

extern "C" void kernel_launch(void* const* d_in, const int* in_sizes, int n_in,
                              void* d_out, int out_size, void* d_ws, size_t ws_size,
                              hipStream_t stream) {
    const float* x = (const float*)d_in[0];
    const float* h = (const float*)d_in[1];
    const float* emb = (const float*)d_in[2];
    const float* tau_off = (const float*)d_in[3];
    const float* w_read = (const float*)d_in[4];
    const float* w_write = (const float*)d_in[5];
    char* ws = (char*)d_ws;
    u16* hb = (u16*)(ws + OFF_HB);
    u16* xb = (u16*)(ws + OFF_XB);
    u16* P = (u16*)(ws + OFF_P);
    u16* ebf = (u16*)(ws + OFF_EBF);
    u16* rbf = (u16*)(ws + OFF_RBF);
    u16* wwT = (u16*)(ws + OFF_WWT);
    float* sw = (float*)(ws + OFF_SW);
    float* rowsum = (float*)(ws + OFF_ROWSUM);
    float* rowsq = (float*)(ws + OFF_ROWSQ);
    float* colsum = (float*)(ws + OFF_COLSUM);
    float* tau = (float*)(ws + OFF_TAU);
    float* invstd = (float*)(ws + OFF_INVSTD);
    float* smean = (float*)(ws + OFF_SMEAN);
    float* sstd = (float*)(ws + OFF_SSTD);
    float* twc = (float*)(ws + OFF_TWC);
    float* act = (float*)(ws + OFF_ACT);
    float* scal = (float*)(ws + OFF_SCAL);
    u16* part = (u16*)(ws + OFF_PART);
    const bool fullA = ws_size >= FULL_END;
    u16* sbP = fullA ? (u16*)(ws + OFF_SB) : (u16*)nullptr;

    float* out0 = (float*)d_out;
    float* out1 = out0 + (size_t)M_TOT * D_DIM;
    float* out2 = out1 + M_TOT;
    float* outS = out2 + M_TOT;

    hipMemsetAsync(ws + OFF_ROWSUM, 0, ZERO_LEN, stream);

    k_cvt<<<4096, 256, 0, stream>>>(h, x, hb, xb);

    if (fullA) {
        k_cvt_ern3<<<dim3(N_NEUR / 4, 3), 256, 0, stream>>>(emb, w_read, w_write,
                                                            ebf, rbf, sw);
        k_tww<<<dim3(N_NEUR / 64, 16), 256, 0, stream>>>(w_write, sw, 0, wwT, N_NEUR);
        k_pass1<<<dim3(32, 256), 256, 0, stream>>>(hb, ebf, 0, rowsum, rowsq, colsum,
                                                   sbP, N_NEUR);
        k_ns<<<128, 256, 0, stream>>>(colsum, scal);
        k_tau<<<16, 256, 0, stream>>>(rowsum, rowsq, tau_off, tau, invstd, smean, sstd);
        k_xr_gate_all<<<dim3(32, 256), 256, 0, stream>>>(xb, rbf, sbP, tau, invstd, twc, act);
        k_pass2b_all<<<dim3(32, 8, 8), 256, 0, stream>>>(sbP, wwT, part);
        k_norm_comb<<<4096, 256, 0, stream>>>(part, twc, act, out0, out1, out2);
    } else {
        hipMemsetAsync(d_out, 0, (size_t)M_TOT * D_DIM * 4, stream);
        k_sw<<<N_NEUR / 4, 256, 0, stream>>>(w_write, sw);
        for (int c = 0; c < NCHUNK; c++) {
            k_cvt_e_norm<<<CS / 4, 256, 0, stream>>>(emb, c * CS, ebf);
            k_pass1<<<dim3(32, 32), 256, 0, stream>>>(hb, ebf, c * CS, rowsum, rowsq, colsum,
                                                      (u16*)nullptr, 0);
        }
        k_ns<<<128, 256, 0, stream>>>(colsum, scal);
        k_tau<<<16, 256, 0, stream>>>(rowsum, rowsq, tau_off, tau, invstd, smean, sstd);
        for (int c = 0; c < NCHUNK; c++) {
            k_cvt_e_norm<<<CS / 4, 256, 0, stream>>>(emb, c * CS, ebf);
            k_cvt_r_norm<<<CS / 4, 256, 0, stream>>>(w_read, c * CS, rbf);
            k_tww<<<dim3(CS / 64, 16), 256, 0, stream>>>(w_write, sw, c * CS, wwT, CS);
            k_xr_plain<<<dim3(32, 32), 256, 0, stream>>>(xb, rbf, P);
            k_gate_gemm<<<dim3(32, 32), 256, 0, stream>>>(hb, ebf, tau, invstd, P, twc, act);
            k_pass2b<<<dim3(32, 8), 256, 0, stream>>>(P, wwT, CS, out0);
        }
        k_norm_f<<<4096, 256, 0, stream>>>(out0, twc, act, out1, out2);
    }
    k_scalars<<<1, 256, 0, stream>>>(smean, sstd, twc, act, scal, outS);
}

// Round 15
// 1508.685 us; speedup vs baseline: 1.2260x; 1.2260x over previous
//
#include <hip/hip_runtime.h>
#include <stdint.h>

// Problem constants (B=4,S=1024,D=1024,N=32768,n_chunks=8)
#define M_TOT 4096
#define D_DIM 1024
#define N_NEUR 32768
#define NCHUNK 8
#define CS 4096

typedef float f32x4 __attribute__((ext_vector_type(4)));
typedef __bf16 bf16x8 __attribute__((ext_vector_type(8)));
typedef unsigned short u16;
typedef unsigned int u32;
typedef u16 u16x8 __attribute__((ext_vector_type(8)));
typedef u16 u16x4 __attribute__((ext_vector_type(4)));

__device__ __forceinline__ u16 f2bf(float f) {
    u32 u = __builtin_bit_cast(u32, f);
    u = (u + 0x7FFFu + ((u >> 16) & 1u)) >> 16;
    return (u16)u;
}
__device__ __forceinline__ float bf2f(u16 h) {
    u32 u = ((u32)h) << 16;
    return __builtin_bit_cast(float, u);
}
__device__ __forceinline__ u32 pack2(float a, float b, float s) {
    return (u32)f2bf(a * s) | ((u32)f2bf(b * s) << 16);
}

typedef __attribute__((address_space(1))) const u32 as1_u32;
typedef __attribute__((address_space(3))) u32 as3_u32;
__device__ __forceinline__ void gload16(const void* g, void* l) {
    __builtin_amdgcn_global_load_lds((as1_u32*)g, (as3_u32*)l, 16, 0, 0);
}

#define MFMA(a, b, c) __builtin_amdgcn_mfma_f32_16x16x32_bf16((a), (b), (c), 0, 0, 0)

// 128x128-tile bf16 GEMM main loop (m97 structure: BK=32, linear LDS,
// global_load_lds width-16, 2 barriers/K-step). Separate A/B row strides.
// LDS[17408] u16 (34 KB): GEMM uses first 8192; the epilogue restage uses the
// full array as 128 rows x stride 136 (max idx 127*136+127 = 17399 < 17408).
// NOTE (R13/R14 lessons): BK=64 regresses (16-way ds_read conflicts, +120us);
// XCD bn-range swizzle regresses (A working set thrashes L2, +320us). Default
// linear block order is near-optimal for this grid. Keep BK=32, no swizzle.
#define GEMM128_BODY(ABASE, ASTR, BBASE, BSTR, KLEN)                                  \
    __shared__ u16 LDS[17408];                                                        \
    u16* Al = LDS;                                                                    \
    u16* Bl = LDS + 4096;                                                             \
    const int t = threadIdx.x, lane = t & 63, w = t >> 6;                             \
    const int wr = w >> 1, wc = w & 1, l15 = lane & 15, lg = lane >> 4;               \
    f32x4 acc[4][4] = {};                                                             \
    {                                                                                 \
        const int rb = lane >> 2, cl = (lane & 3) * 8;                                \
        const int seg0 = w * 2;                                                       \
        const size_t ro0 = (size_t)(seg0 * 16 + rb);                                  \
        const u16* pa0 = (ABASE) + ((size_t)bm * 128 + ro0) * (ASTR) + cl;            \
        const u16* pb0 = (BBASE) + ((size_t)bn * 128 + ro0) * (BSTR) + cl;            \
        const u16* pa1 = pa0 + (size_t)16 * (ASTR);                                   \
        const u16* pb1 = pb0 + (size_t)16 * (BSTR);                                   \
        u16* la0 = Al + seg0 * 512;                                                   \
        u16* lb0 = Bl + seg0 * 512;                                                   \
        for (int k0 = 0; k0 < (KLEN); k0 += 32) {                                     \
            __syncthreads();                                                          \
            gload16(pa0 + k0, la0);                                                   \
            gload16(pa1 + k0, la0 + 512);                                             \
            gload16(pb0 + k0, lb0);                                                   \
            gload16(pb1 + k0, lb0 + 512);                                             \
            __syncthreads();                                                          \
            bf16x8 afr[4], bfr[4];                                                    \
            _Pragma("unroll") for (int m = 0; m < 4; m++)                             \
                afr[m] = *(const bf16x8*)&Al[(wr * 64 + m * 16 + l15) * 32 + lg * 8]; \
            _Pragma("unroll") for (int n = 0; n < 4; n++)                             \
                bfr[n] = *(const bf16x8*)&Bl[(wc * 64 + n * 16 + l15) * 32 + lg * 8]; \
            _Pragma("unroll") for (int m = 0; m < 4; m++)                             \
                _Pragma("unroll") for (int n = 0; n < 4; n++)                         \
                    acc[m][n] = MFMA(afr[m], bfr[n], acc[m][n]);                      \
        }                                                                             \
    }

// Single-pass full-tile restage: fragments -> LDS[128 rows][stride 136].
#define RESTAGE_TO_LDS(VALS)                                                          \
    __syncthreads();                                                                  \
    _Pragma("unroll") for (int m = 0; m < 4; m++)                                     \
        _Pragma("unroll") for (int rr = 0; rr < 4; rr++)                              \
            _Pragma("unroll") for (int n = 0; n < 4; n++) {                           \
                int lrow = wr * 64 + m * 16 + lg * 4 + rr;                            \
                LDS[lrow * 136 + wc * 64 + n * 16 + l15] = (VALS);                    \
            }                                                                         \
    __syncthreads();

// Full-tile row-major u16 writeout via the single restage (two read passes).
#define RESTAGE_U16_TILE(VALS, DSTBASE, DSTSTRIDE, COLBASE)                           \
    {                                                                                 \
        RESTAGE_TO_LDS(VALS)                                                          \
        int row_ = t >> 2, c0_ = (t & 3) * 32;                                        \
        _Pragma("unroll") for (int p = 0; p < 2; p++) {                               \
            int lrow = p * 64 + row_;                                                 \
            u16* dst_ = (DSTBASE) + (size_t)(bm * 128 + lrow) * (DSTSTRIDE) +         \
                        (COLBASE) + c0_;                                              \
            const u16* srcl_ = &LDS[lrow * 136 + c0_];                                \
            _Pragma("unroll") for (int j = 0; j < 4; j++)                             \
                *(u16x8*)(dst_ + j * 8) = *(const u16x8*)(srcl_ + j * 8);             \
        }                                                                             \
    }

// ---------------- prep: h,x -> bf16 ----------------------------------------
__global__ __launch_bounds__(256) void k_cvt(const float* __restrict__ h,
                                             const float* __restrict__ x,
                                             u16* __restrict__ hb, u16* __restrict__ xb) {
    size_t i = ((size_t)blockIdx.x * 256 + threadIdx.x) * 4;
    float4 v = *(const float4*)(h + i);
    uint2 o;
    o.x = pack2(v.x, v.y, 1.0f);
    o.y = pack2(v.z, v.w, 1.0f);
    *(uint2*)(hb + i) = o;
    v = *(const float4*)(x + i);
    o.x = pack2(v.x, v.y, 1.0f);
    o.y = pack2(v.z, v.w, 1.0f);
    *(uint2*)(xb + i) = o;
}

// ---------------- fused norm+convert: y=0 emb->ebf, y=1 w_read->rbf, y=2 sw --
__global__ __launch_bounds__(256) void k_cvt_ern3(const float* __restrict__ emb,
                                                  const float* __restrict__ wrd,
                                                  const float* __restrict__ ww,
                                                  u16* __restrict__ ebf, u16* __restrict__ rbf,
                                                  float* __restrict__ sw) {
    int t = threadIdx.x, lane = t & 63, wv = t >> 6;
    int row = blockIdx.x * 4 + wv;
    int which = blockIdx.y;
    const float* srcm = which == 0 ? emb : (which == 1 ? wrd : ww);
    const float4* src = (const float4*)(srcm + (size_t)row * D_DIM);
    float4 v[4];
    float ss = 0.f;
#pragma unroll
    for (int j = 0; j < 4; j++) {
        v[j] = src[j * 64 + lane];
        if (which == 0) {
            ss += v[j].x * v[j].x + v[j].y * v[j].y + v[j].z * v[j].z + v[j].w * v[j].w;
        } else {
            float a = bf2f(f2bf(v[j].x)), b = bf2f(f2bf(v[j].y));
            float c = bf2f(f2bf(v[j].z)), d = bf2f(f2bf(v[j].w));
            ss += a * a + b * b + c * c + d * d;
        }
    }
#pragma unroll
    for (int s = 1; s < 64; s <<= 1) ss += __shfl_xor(ss, s);
    float sc = 1.0f / (sqrtf(ss) + 1e-8f);
    if (which == 2) {
        if (lane == 0) sw[row] = sc;
        return;
    }
    uint2* dst = (uint2*)((which == 0 ? ebf : rbf) + (size_t)row * D_DIM);
#pragma unroll
    for (int j = 0; j < 4; j++) {
        uint2 o;
        o.x = pack2(v[j].x, v[j].y, sc);
        o.y = pack2(v[j].z, v[j].w, sc);
        dst[j * 64 + lane] = o;
    }
}

// per-chunk variants for the compact fallback path
__global__ __launch_bounds__(256) void k_cvt_e_norm(const float* __restrict__ emb,
                                                    int cbase, u16* __restrict__ ebf) {
    int t = threadIdx.x, lane = t & 63, wv = t >> 6;
    int row = blockIdx.x * 4 + wv;
    const float4* src = (const float4*)(emb + (size_t)(cbase + row) * D_DIM);
    float4 v[4];
    float ss = 0.f;
#pragma unroll
    for (int j = 0; j < 4; j++) {
        v[j] = src[j * 64 + lane];
        ss += v[j].x * v[j].x + v[j].y * v[j].y + v[j].z * v[j].z + v[j].w * v[j].w;
    }
#pragma unroll
    for (int s = 1; s < 64; s <<= 1) ss += __shfl_xor(ss, s);
    float es = 1.0f / (sqrtf(ss) + 1e-8f);
    uint2* dst = (uint2*)(ebf + (size_t)row * D_DIM);
#pragma unroll
    for (int j = 0; j < 4; j++) {
        uint2 o;
        o.x = pack2(v[j].x, v[j].y, es);
        o.y = pack2(v[j].z, v[j].w, es);
        dst[j * 64 + lane] = o;
    }
}

__global__ __launch_bounds__(256) void k_cvt_r_norm(const float* __restrict__ wrd,
                                                    int cbase, u16* __restrict__ rbf) {
    int t = threadIdx.x, lane = t & 63, wv = t >> 6;
    int row = blockIdx.x * 4 + wv;
    const float4* src = (const float4*)(wrd + (size_t)(cbase + row) * D_DIM);
    float4 v[4];
    float ss = 0.f;
#pragma unroll
    for (int j = 0; j < 4; j++) {
        v[j] = src[j * 64 + lane];
        float a = bf2f(f2bf(v[j].x)), b = bf2f(f2bf(v[j].y));
        float c = bf2f(f2bf(v[j].z)), d = bf2f(f2bf(v[j].w));
        ss += a * a + b * b + c * c + d * d;
    }
#pragma unroll
    for (int s = 1; s < 64; s <<= 1) ss += __shfl_xor(ss, s);
    float rs = 1.0f / (sqrtf(ss) + 1e-8f);
    uint2* dst = (uint2*)(rbf + (size_t)row * D_DIM);
#pragma unroll
    for (int j = 0; j < 4; j++) {
        uint2 o;
        o.x = pack2(v[j].x, v[j].y, rs);
        o.y = pack2(v[j].z, v[j].w, rs);
        dst[j * 64 + lane] = o;
    }
}

// ---------------- w_write row norms (fallback path) ---------------------------
__global__ __launch_bounds__(256) void k_sw(const float* __restrict__ ww, float* sw) {
    int t = threadIdx.x, lane = t & 63, wv = t >> 6;
    int row = blockIdx.x * 4 + wv;
    const float4* src = (const float4*)(ww + (size_t)row * D_DIM);
    float ss = 0.f;
#pragma unroll
    for (int j = 0; j < 4; j++) {
        float4 v = src[j * 64 + lane];
        float a = bf2f(f2bf(v.x)), b = bf2f(f2bf(v.y));
        float c = bf2f(f2bf(v.z)), d = bf2f(f2bf(v.w));
        ss += a * a + b * b + c * c + d * d;
    }
#pragma unroll
    for (int s = 1; s < 64; s <<= 1) ss += __shfl_xor(ss, s);
    if (lane == 0) sw[row] = 1.0f / (sqrtf(ss) + 1e-8f);
}

// ---------------- transpose w_write -> wwT[d][k] bf16 ------------------------
__global__ __launch_bounds__(256) void k_tww(const float* __restrict__ ww,
                                             const float* __restrict__ sw,
                                             int cbase, u16* __restrict__ wwT, int dstr) {
    __shared__ u16 tile[64][80];
    int kt = blockIdx.x * 64;
    int dt = blockIdx.y * 64;
    int t = threadIdx.x;
    int kk = t >> 4;
    int dd = (t & 15) * 4;
#pragma unroll
    for (int i = 0; i < 4; i++) {
        int krow = kk + i * 16;
        int kg = cbase + kt + krow;
        float s = sw[kg];
        float4 v = *(const float4*)(ww + (size_t)kg * D_DIM + dt + dd);
        tile[dd + 0][krow] = f2bf(v.x * s);
        tile[dd + 1][krow] = f2bf(v.y * s);
        tile[dd + 2][krow] = f2bf(v.z * s);
        tile[dd + 3][krow] = f2bf(v.w * s);
    }
    __syncthreads();
    int dd2 = t >> 2;
    int kk2 = (t & 3) * 16;
    uint4 o0 = *(const uint4*)&tile[dd2][kk2];
    uint4 o1 = *(const uint4*)&tile[dd2][kk2 + 8];
    u16* dst = wwT + (size_t)(dt + dd2) * dstr + kt + kk2;
    *(uint4*)dst = o0;
    *(uint4*)(dst + 8) = o1;
}

// ---------------- pass 1: scores GEMM + stats + row-major sb ------------------
__global__ __launch_bounds__(256) void k_pass1(const u16* __restrict__ hb,
                                               const u16* __restrict__ ebf, int cbase,
                                               float* rowsum, float* rowsq, float* colsum,
                                               u16* __restrict__ sb, int sstr) {
    int bm = blockIdx.x, bn = blockIdx.y;
    GEMM128_BODY(hb, D_DIM, ebf, D_DIM, D_DIM)
    // column sums from fragments (bf16-rounded values)
    float csv[4] = {0.f, 0.f, 0.f, 0.f};
#pragma unroll
    for (int m = 0; m < 4; m++)
#pragma unroll
        for (int rr = 0; rr < 4; rr++)
#pragma unroll
            for (int n = 0; n < 4; n++) csv[n] += bf2f(f2bf(acc[m][n][rr]));
#pragma unroll
    for (int n = 0; n < 4; n++) {
        float cv = csv[n];
        cv += __shfl_xor(cv, 16);
        cv += __shfl_xor(cv, 32);
        if (lg == 0) {
            int ng = cbase + bn * 128 + wc * 64 + n * 16 + l15;
            atomicAdd(&colsum[ng], cv);
        }
    }
    // restage full tile once; row stats + coalesced sb store in two passes
    RESTAGE_TO_LDS(f2bf(acc[m][n][rr]))
    int row_ = t >> 2, c0_ = (t & 3) * 32;
#pragma unroll
    for (int p = 0; p < 2; p++) {
        int lrow = p * 64 + row_;
        int grow = bm * 128 + lrow;
        float rs = 0.f, rq = 0.f;
        u16* dst = sb ? (sb + (size_t)grow * sstr + cbase + bn * 128 + c0_) : (u16*)nullptr;
#pragma unroll
        for (int j = 0; j < 4; j++) {
            u16x8 v = *(const u16x8*)&LDS[lrow * 136 + c0_ + j * 8];
            if (dst) *(u16x8*)(dst + j * 8) = v;
#pragma unroll
            for (int q = 0; q < 8; q++) {
                float sv = bf2f(v[q]);
                rs += sv;
                rq += sv * sv;
            }
        }
        rs += __shfl_xor(rs, 1);
        rq += __shfl_xor(rq, 1);
        rs += __shfl_xor(rs, 2);
        rq += __shfl_xor(rq, 2);
        if ((lane & 3) == 0) {
            atomicAdd(&rowsum[grow], rs);
            atomicAdd(&rowsq[grow], rq);
        }
    }
}

// ---------------- ns stats reduce -------------------------------------------
__global__ __launch_bounds__(256) void k_ns(const float* __restrict__ colsum, float* scal) {
    int i = blockIdx.x * 256 + threadIdx.x;
    float pm = colsum[i] * (1.0f / 4096.0f);
    float s1 = pm, s2 = pm * pm;
#pragma unroll
    for (int x = 1; x < 64; x <<= 1) {
        s1 += __shfl_xor(s1, x);
        s2 += __shfl_xor(s2, x);
    }
    __shared__ float sh[2][4];
    int w = threadIdx.x >> 6;
    if ((threadIdx.x & 63) == 0) { sh[0][w] = s1; sh[1][w] = s2; }
    __syncthreads();
    if (threadIdx.x == 0) {
        atomicAdd(&scal[0], sh[0][0] + sh[0][1] + sh[0][2] + sh[0][3]);
        atomicAdd(&scal[1], sh[1][0] + sh[1][1] + sh[1][2] + sh[1][3]);
    }
}

// ---------------- tau --------------------------------------------------------
__global__ __launch_bounds__(256) void k_tau(const float* __restrict__ rowsum,
                                             const float* __restrict__ rowsq,
                                             const float* __restrict__ tau_off,
                                             float* tau, float* invstd, float* smean, float* sstd) {
    int i = blockIdx.x * 256 + threadIdx.x;
    float sm = rowsum[i] * (1.0f / 32768.0f);
    float var = rowsq[i] * (1.0f / 32768.0f) - sm * sm;
    float sd = sqrtf(var) + 1e-8f;
    smean[i] = sm;
    sstd[i] = sd;
    invstd[i] = 1.0f / sd;
    tau[i] = sm + tau_off[i] * sd;
}

// ---------------- flow A: xr GEMM + gate, P in-place into sb ------------------
__global__ __launch_bounds__(256) void k_xr_gate_all(const u16* __restrict__ xb,
                                                     const u16* __restrict__ rbf,
                                                     u16* __restrict__ sbP,
                                                     const float* __restrict__ tau,
                                                     const float* __restrict__ invstd,
                                                     float* twc, float* act) {
    int bm = blockIdx.x, bn = blockIdx.y;
    const int tt = threadIdx.x;
    const int prow = tt >> 2, pc0 = (tt & 3) * 32;
    u16x8 sv_pre[2][4];
#pragma unroll
    for (int p = 0; p < 2; p++) {
        int grow = bm * 128 + p * 64 + prow;
        const u16* src = sbP + (size_t)grow * N_NEUR + bn * 128 + pc0;
#pragma unroll
        for (int j = 0; j < 4; j++) sv_pre[p][j] = *(const u16x8*)(src + j * 8);
    }
    GEMM128_BODY(xb, D_DIM, rbf, D_DIM, D_DIM)
    RESTAGE_TO_LDS(f2bf(acc[m][n][rr]))
#pragma unroll
    for (int p = 0; p < 2; p++) {
        int lrow = p * 64 + prow;
        int grow = bm * 128 + lrow;
        float tl = tau[grow], il = invstd[grow];
        float wsum = 0.f, cnt = 0.f;
        u16* gptr = sbP + (size_t)grow * N_NEUR + bn * 128 + pc0;
#pragma unroll
        for (int j = 0; j < 4; j++) {
            u16x8 xr8 = *(const u16x8*)&LDS[lrow * 136 + pc0 + j * 8];
            u16x8 sv8 = sv_pre[p][j];
            u16x8 o;
#pragma unroll
            for (int q = 0; q < 8; q++) {
                float xf = bf2f(xr8[q]);
                float raw = bf2f(sv8[q]) - tl;
                float sig = 1.0f / (1.0f + __expf(-raw * il));
                bool g = raw > 0.0f;
                wsum += sig * xf * xf;
                cnt += g ? 1.0f : 0.0f;
                o[q] = g ? xr8[q] : (u16)0;
            }
            *(u16x8*)(gptr + j * 8) = o;
        }
        wsum += __shfl_xor(wsum, 1);
        cnt += __shfl_xor(cnt, 1);
        wsum += __shfl_xor(wsum, 2);
        cnt += __shfl_xor(cnt, 2);
        if ((lane & 3) == 0) {
            atomicAdd(&twc[grow], wsum);
            atomicAdd(&act[grow], cnt);
        }
    }
}

// ---------------- flow A: all-chunk write GEMM -> bf16 partials --------------
__global__ __launch_bounds__(256) void k_pass2b_all(const u16* __restrict__ sbP,
                                                    const u16* __restrict__ wwT,
                                                    u16* __restrict__ part) {
    int bm = blockIdx.x;
    int bn = blockIdx.y;
    int zz = blockIdx.z;
    const u16* Pz = sbP + (size_t)zz * CS;
    const u16* Wz = wwT + (size_t)zz * CS;
    u16* pz = part + (size_t)zz * M_TOT * D_DIM;
    GEMM128_BODY(Pz, N_NEUR, Wz, N_NEUR, CS)
    RESTAGE_U16_TILE(f2bf(acc[m][n][rr]), pz, D_DIM, bn * 128)
}

// ---------------- final: sum bf16 partials, normalize, per-row outputs -------
__global__ __launch_bounds__(256) void k_norm_comb(const u16* __restrict__ part,
                                                   const float* __restrict__ twc,
                                                   const float* __restrict__ act,
                                                   float* __restrict__ out0,
                                                   float* out1, float* out2) {
    int row = blockIdx.x;
    float den = sqrtf(twc[row] + 1e-6f);
    den = fmaxf(den, 0.001f);
    float inv = 1.0f / den;
    size_t base = (size_t)row * D_DIM + threadIdx.x * 4;
    float s0 = 0.f, s1 = 0.f, s2 = 0.f, s3 = 0.f;
#pragma unroll
    for (int c = 0; c < NCHUNK; c++) {
        u16x4 v = *(const u16x4*)(part + (size_t)c * M_TOT * D_DIM + base);
        s0 += bf2f(v[0]);
        s1 += bf2f(v[1]);
        s2 += bf2f(v[2]);
        s3 += bf2f(v[3]);
    }
    float4 o;
    o.x = bf2f(f2bf(s0 * inv));
    o.y = bf2f(f2bf(s1 * inv));
    o.z = bf2f(f2bf(s2 * inv));
    o.w = bf2f(f2bf(s3 * inv));
    *(float4*)(out0 + base) = o;
    if (threadIdx.x == 0) {
        out1[row] = act[row] * (1.0f / 32768.0f);
        out2[row] = act[row] > 0.0f ? 1.0f : 0.0f;
    }
}

// ---------------- flow B kernels (compact fallback) ---------------------------
__global__ __launch_bounds__(256) void k_xr_plain(const u16* __restrict__ xb,
                                                  const u16* __restrict__ rbf,
                                                  u16* __restrict__ P) {
    int bm = blockIdx.x, bn = blockIdx.y;
    GEMM128_BODY(xb, D_DIM, rbf, D_DIM, D_DIM)
    RESTAGE_U16_TILE(f2bf(acc[m][n][rr]), P, CS, bn * 128)
}

__global__ __launch_bounds__(256) void k_gate_gemm(const u16* __restrict__ hb,
                                                   const u16* __restrict__ ebf,
                                                   const float* __restrict__ tau,
                                                   const float* __restrict__ invstd,
                                                   u16* __restrict__ P, float* twc, float* act) {
    int bm = blockIdx.x, bn = blockIdx.y;
    GEMM128_BODY(hb, D_DIM, ebf, D_DIM, D_DIM)
#pragma unroll
    for (int m = 0; m < 4; m++) {
#pragma unroll
        for (int rr = 0; rr < 4; rr++) {
            int mg = bm * 128 + wr * 64 + m * 16 + lg * 4 + rr;
            float tl = tau[mg], il = invstd[mg];
            float wsum = 0.f, cnt = 0.f;
#pragma unroll
            for (int n = 0; n < 4; n++) {
                int ngl = bn * 128 + wc * 64 + n * 16 + l15;
                float sv = bf2f(f2bf(acc[m][n][rr]));
                float raw = sv - tl;
                u16 xrb = P[(size_t)mg * CS + ngl];
                float xf = bf2f(xrb);
                float sig = 1.0f / (1.0f + __expf(-raw * il));
                bool g = raw > 0.0f;
                wsum += sig * xf * xf;
                cnt += g ? 1.0f : 0.0f;
                P[(size_t)mg * CS + ngl] = g ? xrb : (u16)0;
            }
#pragma unroll
            for (int x = 1; x < 16; x <<= 1) {
                wsum += __shfl_xor(wsum, x);
                cnt += __shfl_xor(cnt, x);
            }
            if (l15 == 0) {
                atomicAdd(&twc[mg], wsum);
                atomicAdd(&act[mg], cnt);
            }
        }
    }
}

__global__ __launch_bounds__(256) void k_pass2b(const u16* __restrict__ P,
                                                const u16* __restrict__ wwT, int bstr,
                                                float* __restrict__ out) {
    int bm = blockIdx.x;
    int bn = blockIdx.y;
    GEMM128_BODY(P, CS, wwT, bstr, CS)
#pragma unroll
    for (int m = 0; m < 4; m++)
#pragma unroll
        for (int n = 0; n < 4; n++)
#pragma unroll
            for (int rr = 0; rr < 4; rr++) {
                int mg = bm * 128 + wr * 64 + m * 16 + lg * 4 + rr;
                int dg = bn * 128 + wc * 64 + n * 16 + l15;
                out[(size_t)mg * D_DIM + dg] += bf2f(f2bf(acc[m][n][rr]));
            }
}

__global__ __launch_bounds__(256) void k_norm_f(float* __restrict__ out,
                                                const float* __restrict__ twc,
                                                const float* __restrict__ act,
                                                float* out1, float* out2) {
    int row = blockIdx.x;
    float den = sqrtf(twc[row] + 1e-6f);
    den = fmaxf(den, 0.001f);
    float inv = 1.0f / den;
    float* p = out + (size_t)row * D_DIM;
    int i = threadIdx.x * 4;
    float4 v = *(float4*)(p + i);
    v.x = bf2f(f2bf(v.x * inv));
    v.y = bf2f(f2bf(v.y * inv));
    v.z = bf2f(f2bf(v.z * inv));
    v.w = bf2f(f2bf(v.w * inv));
    *(float4*)(p + i) = v;
    if (threadIdx.x == 0) {
        out1[row] = act[row] * (1.0f / 32768.0f);
        out2[row] = act[row] > 0.0f ? 1.0f : 0.0f;
    }
}

// ---------------- scalar outputs ---------------------------------------------
__global__ __launch_bounds__(256) void k_scalars(const float* __restrict__ smean,
                                                 const float* __restrict__ sstd,
                                                 const float* __restrict__ twc,
                                                 const float* __restrict__ act,
                                                 const float* __restrict__ scal,
                                                 float* outS) {
    float a = 0.f, b = 0.f, c = 0.f, d = 0.f;
    for (int i = threadIdx.x; i < 4096; i += 256) {
        a += smean[i];
        b += sstd[i];
        c += twc[i];
        d += act[i];
    }
#pragma unroll
    for (int x = 1; x < 64; x <<= 1) {
        a += __shfl_xor(a, x);
        b += __shfl_xor(b, x);
        c += __shfl_xor(c, x);
        d += __shfl_xor(d, x);
    }
    __shared__ float sh[4][4];
    int w = threadIdx.x >> 6;
    if ((threadIdx.x & 63) == 0) { sh[0][w] = a; sh[1][w] = b; sh[2][w] = c; sh[3][w] = d; }
    __syncthreads();
    if (threadIdx.x == 0) {
        float ma = sh[0][0] + sh[0][1] + sh[0][2] + sh[0][3];
        float mb = sh[1][0] + sh[1][1] + sh[1][2] + sh[1][3];
        float mc = sh[2][0] + sh[2][1] + sh[2][2] + sh[2][3];
        float md = sh[3][0] + sh[3][1] + sh[3][2] + sh[3][3];
        float mean_score = scal[0] * (1.0f / 32768.0f);
        float var_score = scal[1] * (1.0f / 32768.0f) - mean_score * mean_score;
        outS[0] = var_score / (mean_score * mean_score + var_score + 0.01f);  // score_lb
        outS[1] = mb * (1.0f / 4096.0f);                                      // score_std_out
        outS[2] = mc * (1.0f / 4096.0f);                                      // es_out
        outS[3] = md * (1.0f / 4096.0f);                                      // active_n_mean
        outS[4] = ma * (1.0f / 4096.0f);                                      // score_mean_out
    }
}

// ---------------- workspace layout (bytes) -----------------------------------
static constexpr size_t OFF_HB     = 0;           // 8 MB
static constexpr size_t OFF_XB     = 8388608;     // 8 MB
static constexpr size_t OFF_P      = 16777216;    // 32 MB (fallback only)
static constexpr size_t OFF_EBF    = 50331648;    // 64 MB; part (64 MB bf16) overlays
static constexpr size_t OFF_RBF    = 117440512;   // 64 MB
static constexpr size_t OFF_WWT    = 184549376;   // 64 MB  [D][N] (flow A) / [D][CS] fallback
static constexpr size_t OFF_SW     = 251658240;   // 128 KB
static constexpr size_t OFF_ROWSUM = 251789312;
static constexpr size_t OFF_ROWSQ  = 251805696;
static constexpr size_t OFF_COLSUM = 251822080;   // 128 KB
static constexpr size_t OFF_TAU    = 251953152;
static constexpr size_t OFF_INVSTD = 251969536;
static constexpr size_t OFF_SMEAN  = 251985920;
static constexpr size_t OFF_SSTD   = 252002304;
static constexpr size_t OFF_TWC    = 252018688;
static constexpr size_t OFF_ACT    = 252035072;
static constexpr size_t OFF_SCAL   = 252051456;
static constexpr size_t STATS_END  = 252051520;
static constexpr size_t ZERO_LEN   = STATS_END - OFF_ROWSUM;
static constexpr size_t OFF_SB     = 252706816;   // 256 MB (flow A) scores -> gated P
static constexpr size_t FULL_END   = OFF_SB + (size_t)M_TOT * N_NEUR * 2;  // ~497 MB
static constexpr size_t OFF_PART   = OFF_EBF;     // 64 MB bf16 partials overlay

extern "C" void kernel_launch(void* const* d_in, const int* in_sizes, int n_in,
                              void* d_out, int out_size, void* d_ws, size_t ws_size,
                              hipStream_t stream) {
    const float* x = (const float*)d_in[0];
    const float* h = (const float*)d_in[1];
    const float* emb = (const float*)d_in[2];
    const float* tau_off = (const float*)d_in[3];
    const float* w_read = (const float*)d_in[4];
    const float* w_write = (const float*)d_in[5];
    char* ws = (char*)d_ws;
    u16* hb = (u16*)(ws + OFF_HB);
    u16* xb = (u16*)(ws + OFF_XB);
    u16* P = (u16*)(ws + OFF_P);
    u16* ebf = (u16*)(ws + OFF_EBF);
    u16* rbf = (u16*)(ws + OFF_RBF);
    u16* wwT = (u16*)(ws + OFF_WWT);
    float* sw = (float*)(ws + OFF_SW);
    float* rowsum = (float*)(ws + OFF_ROWSUM);
    float* rowsq = (float*)(ws + OFF_ROWSQ);
    float* colsum = (float*)(ws + OFF_COLSUM);
    float* tau = (float*)(ws + OFF_TAU);
    float* invstd = (float*)(ws + OFF_INVSTD);
    float* smean = (float*)(ws + OFF_SMEAN);
    float* sstd = (float*)(ws + OFF_SSTD);
    float* twc = (float*)(ws + OFF_TWC);
    float* act = (float*)(ws + OFF_ACT);
    float* scal = (float*)(ws + OFF_SCAL);
    u16* part = (u16*)(ws + OFF_PART);
    const bool fullA = ws_size >= FULL_END;
    u16* sbP = fullA ? (u16*)(ws + OFF_SB) : (u16*)nullptr;

    float* out0 = (float*)d_out;
    float* out1 = out0 + (size_t)M_TOT * D_DIM;
    float* out2 = out1 + M_TOT;
    float* outS = out2 + M_TOT;

    hipMemsetAsync(ws + OFF_ROWSUM, 0, ZERO_LEN, stream);

    k_cvt<<<4096, 256, 0, stream>>>(h, x, hb, xb);

    if (fullA) {
        k_cvt_ern3<<<dim3(N_NEUR / 4, 3), 256, 0, stream>>>(emb, w_read, w_write,
                                                            ebf, rbf, sw);
        k_tww<<<dim3(N_NEUR / 64, 16), 256, 0, stream>>>(w_write, sw, 0, wwT, N_NEUR);
        k_pass1<<<dim3(32, 256), 256, 0, stream>>>(hb, ebf, 0, rowsum, rowsq, colsum,
                                                   sbP, N_NEUR);
        k_ns<<<128, 256, 0, stream>>>(colsum, scal);
        k_tau<<<16, 256, 0, stream>>>(rowsum, rowsq, tau_off, tau, invstd, smean, sstd);
        k_xr_gate_all<<<dim3(32, 256), 256, 0, stream>>>(xb, rbf, sbP, tau, invstd, twc, act);
        k_pass2b_all<<<dim3(32, 8, 8), 256, 0, stream>>>(sbP, wwT, part);
        k_norm_comb<<<4096, 256, 0, stream>>>(part, twc, act, out0, out1, out2);
    } else {
        hipMemsetAsync(d_out, 0, (size_t)M_TOT * D_DIM * 4, stream);
        k_sw<<<N_NEUR / 4, 256, 0, stream>>>(w_write, sw);
        for (int c = 0; c < NCHUNK; c++) {
            k_cvt_e_norm<<<CS / 4, 256, 0, stream>>>(emb, c * CS, ebf);
            k_pass1<<<dim3(32, 32), 256, 0, stream>>>(hb, ebf, c * CS, rowsum, rowsq, colsum,
                                                      (u16*)nullptr, 0);
        }
        k_ns<<<128, 256, 0, stream>>>(colsum, scal);
        k_tau<<<16, 256, 0, stream>>>(rowsum, rowsq, tau_off, tau, invstd, smean, sstd);
        for (int c = 0; c < NCHUNK; c++) {
            k_cvt_e_norm<<<CS / 4, 256, 0, stream>>>(emb, c * CS, ebf);
            k_cvt_r_norm<<<CS / 4, 256, 0, stream>>>(w_read, c * CS, rbf);
            k_tww<<<dim3(CS / 64, 16), 256, 0, stream>>>(w_write, sw, c * CS, wwT, CS);
            k_xr_plain<<<dim3(32, 32), 256, 0, stream>>>(xb, rbf, P);
            k_gate_gemm<<<dim3(32, 32), 256, 0, stream>>>(hb, ebf, tau, invstd, P, twc, act);
            k_pass2b<<<dim3(32, 8), 256, 0, stream>>>(P, wwT, CS, out0);
        }
        k_norm_f<<<4096, 256, 0, stream>>>(out0, twc, act, out1, out2);
    }
    k_scalars<<<1, 256, 0, stream>>>(smean, sstd, twc, act, scal, outS);
}

// Round 16
// 1480.425 us; speedup vs baseline: 1.2494x; 1.0191x over previous
//
#include <hip/hip_runtime.h>
#include <stdint.h>

// Problem constants (B=4,S=1024,D=1024,N=32768,n_chunks=8)
#define M_TOT 4096
#define D_DIM 1024
#define N_NEUR 32768
#define NCHUNK 8
#define CS 4096

typedef float f32x4 __attribute__((ext_vector_type(4)));
typedef __bf16 bf16x8 __attribute__((ext_vector_type(8)));
typedef unsigned short u16;
typedef unsigned int u32;
typedef u16 u16x8 __attribute__((ext_vector_type(8)));
typedef u16 u16x4 __attribute__((ext_vector_type(4)));

__device__ __forceinline__ u16 f2bf(float f) {
    u32 u = __builtin_bit_cast(u32, f);
    u = (u + 0x7FFFu + ((u >> 16) & 1u)) >> 16;
    return (u16)u;
}
__device__ __forceinline__ float bf2f(u16 h) {
    u32 u = ((u32)h) << 16;
    return __builtin_bit_cast(float, u);
}
__device__ __forceinline__ u32 pack2(float a, float b, float s) {
    return (u32)f2bf(a * s) | ((u32)f2bf(b * s) << 16);
}

typedef __attribute__((address_space(1))) const u32 as1_u32;
typedef __attribute__((address_space(3))) u32 as3_u32;
__device__ __forceinline__ void gload16(const void* g, void* l) {
    __builtin_amdgcn_global_load_lds((as1_u32*)g, (as3_u32*)l, 16, 0, 0);
}

#define MFMA(a, b, c) __builtin_amdgcn_mfma_f32_16x16x32_bf16((a), (b), (c), 0, 0, 0)

// 128x128-tile bf16 GEMM main loop, depth-2 pipelined (T4 counted vmcnt):
// double-buffered LDS; per K-step issue next tile's 4 global_load_lds, then
// s_waitcnt vmcnt(4) (own newest 4 stay in flight; current buf complete),
// raw s_barrier, ds_read+MFMA, s_barrier. vmcnt never drains to 0 mid-loop.
// Race-freedom: barrier#1 publishes buf[i] (each wave's vmcnt(4) retires its
// buf[i] loads first); barrier#2 keeps iteration i+1's staging from
// overwriting buf[i-1] while still being read.
// LDS[17408] u16 (34 KB): buf0 A [0,4096) B [4096,8192); buf1 A [8192,12288)
// B [12288,16384). Epilogue restage reuses full array (128 rows x 136).
// (R13: BK=64 regressed, 16-way conflicts. R14: XCD bn-swizzle regressed,
// L2 thrash. Keep BK=32, linear block order.)
#define GEMM128_BODY(ABASE, ASTR, BBASE, BSTR, KLEN)                                  \
    __shared__ u16 LDS[17408];                                                        \
    const int t = threadIdx.x, lane = t & 63, w = t >> 6;                             \
    const int wr = w >> 1, wc = w & 1, l15 = lane & 15, lg = lane >> 4;               \
    f32x4 acc[4][4] = {};                                                             \
    {                                                                                 \
        const int seg0 = w * 2;                                                       \
        const int rb = lane >> 2, cl = (lane & 3) * 8;                                \
        const size_t ro0 = (size_t)(seg0 * 16 + rb);                                  \
        const u16* pa0 = (ABASE) + ((size_t)bm * 128 + ro0) * (ASTR) + cl;            \
        const u16* pb0 = (BBASE) + ((size_t)bn * 128 + ro0) * (BSTR) + cl;            \
        const u16* pa1 = pa0 + (size_t)16 * (ASTR);                                   \
        const u16* pb1 = pb0 + (size_t)16 * (BSTR);                                   \
        gload16(pa0, LDS + seg0 * 512);                                               \
        gload16(pa1, LDS + seg0 * 512 + 512);                                         \
        gload16(pb0, LDS + 4096 + seg0 * 512);                                        \
        gload16(pb1, LDS + 4096 + seg0 * 512 + 512);                                  \
        for (int k0 = 0; k0 < (KLEN); k0 += 32) {                                     \
            const int co = ((k0 >> 5) & 1) * 8192;                                    \
            const int no = co ^ 8192;                                                 \
            if (k0 + 32 < (KLEN)) {                                                   \
                gload16(pa0 + k0 + 32, LDS + no + seg0 * 512);                        \
                gload16(pa1 + k0 + 32, LDS + no + seg0 * 512 + 512);                  \
                gload16(pb0 + k0 + 32, LDS + no + 4096 + seg0 * 512);                 \
                gload16(pb1 + k0 + 32, LDS + no + 4096 + seg0 * 512 + 512);           \
                asm volatile("s_waitcnt vmcnt(4)" ::: "memory");                      \
            } else {                                                                  \
                asm volatile("s_waitcnt vmcnt(0)" ::: "memory");                      \
            }                                                                         \
            __builtin_amdgcn_s_barrier();                                             \
            bf16x8 afr[4], bfr[4];                                                    \
            _Pragma("unroll") for (int m = 0; m < 4; m++)                             \
                afr[m] = *(const bf16x8*)&LDS[co + (wr * 64 + m * 16 + l15) * 32 +    \
                                              lg * 8];                                \
            _Pragma("unroll") for (int n = 0; n < 4; n++)                             \
                bfr[n] = *(const bf16x8*)&LDS[co + 4096 +                             \
                                              (wc * 64 + n * 16 + l15) * 32 + lg * 8];\
            _Pragma("unroll") for (int m = 0; m < 4; m++)                             \
                _Pragma("unroll") for (int n = 0; n < 4; n++)                         \
                    acc[m][n] = MFMA(afr[m], bfr[n], acc[m][n]);                      \
            __builtin_amdgcn_s_barrier();                                             \
        }                                                                             \
    }

// Single-pass full-tile restage: fragments -> LDS[128 rows][stride 136].
#define RESTAGE_TO_LDS(VALS)                                                          \
    __syncthreads();                                                                  \
    _Pragma("unroll") for (int m = 0; m < 4; m++)                                     \
        _Pragma("unroll") for (int rr = 0; rr < 4; rr++)                              \
            _Pragma("unroll") for (int n = 0; n < 4; n++) {                           \
                int lrow = wr * 64 + m * 16 + lg * 4 + rr;                            \
                LDS[lrow * 136 + wc * 64 + n * 16 + l15] = (VALS);                    \
            }                                                                         \
    __syncthreads();

// Full-tile row-major u16 writeout via the single restage (two read passes).
#define RESTAGE_U16_TILE(VALS, DSTBASE, DSTSTRIDE, COLBASE)                           \
    {                                                                                 \
        RESTAGE_TO_LDS(VALS)                                                          \
        int row_ = t >> 2, c0_ = (t & 3) * 32;                                        \
        _Pragma("unroll") for (int p = 0; p < 2; p++) {                               \
            int lrow = p * 64 + row_;                                                 \
            u16* dst_ = (DSTBASE) + (size_t)(bm * 128 + lrow) * (DSTSTRIDE) +         \
                        (COLBASE) + c0_;                                              \
            const u16* srcl_ = &LDS[lrow * 136 + c0_];                                \
            _Pragma("unroll") for (int j = 0; j < 4; j++)                             \
                *(u16x8*)(dst_ + j * 8) = *(const u16x8*)(srcl_ + j * 8);             \
        }                                                                             \
    }

// ---------------- prep: h,x -> bf16 ----------------------------------------
__global__ __launch_bounds__(256) void k_cvt(const float* __restrict__ h,
                                             const float* __restrict__ x,
                                             u16* __restrict__ hb, u16* __restrict__ xb) {
    size_t i = ((size_t)blockIdx.x * 256 + threadIdx.x) * 4;
    float4 v = *(const float4*)(h + i);
    uint2 o;
    o.x = pack2(v.x, v.y, 1.0f);
    o.y = pack2(v.z, v.w, 1.0f);
    *(uint2*)(hb + i) = o;
    v = *(const float4*)(x + i);
    o.x = pack2(v.x, v.y, 1.0f);
    o.y = pack2(v.z, v.w, 1.0f);
    *(uint2*)(xb + i) = o;
}

// ---------------- fused norm+convert: y=0 emb->ebf, y=1 w_read->rbf, y=2 sw --
__global__ __launch_bounds__(256) void k_cvt_ern3(const float* __restrict__ emb,
                                                  const float* __restrict__ wrd,
                                                  const float* __restrict__ ww,
                                                  u16* __restrict__ ebf, u16* __restrict__ rbf,
                                                  float* __restrict__ sw) {
    int t = threadIdx.x, lane = t & 63, wv = t >> 6;
    int row = blockIdx.x * 4 + wv;
    int which = blockIdx.y;
    const float* srcm = which == 0 ? emb : (which == 1 ? wrd : ww);
    const float4* src = (const float4*)(srcm + (size_t)row * D_DIM);
    float4 v[4];
    float ss = 0.f;
#pragma unroll
    for (int j = 0; j < 4; j++) {
        v[j] = src[j * 64 + lane];
        if (which == 0) {
            ss += v[j].x * v[j].x + v[j].y * v[j].y + v[j].z * v[j].z + v[j].w * v[j].w;
        } else {
            float a = bf2f(f2bf(v[j].x)), b = bf2f(f2bf(v[j].y));
            float c = bf2f(f2bf(v[j].z)), d = bf2f(f2bf(v[j].w));
            ss += a * a + b * b + c * c + d * d;
        }
    }
#pragma unroll
    for (int s = 1; s < 64; s <<= 1) ss += __shfl_xor(ss, s);
    float sc = 1.0f / (sqrtf(ss) + 1e-8f);
    if (which == 2) {
        if (lane == 0) sw[row] = sc;
        return;
    }
    uint2* dst = (uint2*)((which == 0 ? ebf : rbf) + (size_t)row * D_DIM);
#pragma unroll
    for (int j = 0; j < 4; j++) {
        uint2 o;
        o.x = pack2(v[j].x, v[j].y, sc);
        o.y = pack2(v[j].z, v[j].w, sc);
        dst[j * 64 + lane] = o;
    }
}

// per-chunk variants for the compact fallback path
__global__ __launch_bounds__(256) void k_cvt_e_norm(const float* __restrict__ emb,
                                                    int cbase, u16* __restrict__ ebf) {
    int t = threadIdx.x, lane = t & 63, wv = t >> 6;
    int row = blockIdx.x * 4 + wv;
    const float4* src = (const float4*)(emb + (size_t)(cbase + row) * D_DIM);
    float4 v[4];
    float ss = 0.f;
#pragma unroll
    for (int j = 0; j < 4; j++) {
        v[j] = src[j * 64 + lane];
        ss += v[j].x * v[j].x + v[j].y * v[j].y + v[j].z * v[j].z + v[j].w * v[j].w;
    }
#pragma unroll
    for (int s = 1; s < 64; s <<= 1) ss += __shfl_xor(ss, s);
    float es = 1.0f / (sqrtf(ss) + 1e-8f);
    uint2* dst = (uint2*)(ebf + (size_t)row * D_DIM);
#pragma unroll
    for (int j = 0; j < 4; j++) {
        uint2 o;
        o.x = pack2(v[j].x, v[j].y, es);
        o.y = pack2(v[j].z, v[j].w, es);
        dst[j * 64 + lane] = o;
    }
}

__global__ __launch_bounds__(256) void k_cvt_r_norm(const float* __restrict__ wrd,
                                                    int cbase, u16* __restrict__ rbf) {
    int t = threadIdx.x, lane = t & 63, wv = t >> 6;
    int row = blockIdx.x * 4 + wv;
    const float4* src = (const float4*)(wrd + (size_t)(cbase + row) * D_DIM);
    float4 v[4];
    float ss = 0.f;
#pragma unroll
    for (int j = 0; j < 4; j++) {
        v[j] = src[j * 64 + lane];
        float a = bf2f(f2bf(v[j].x)), b = bf2f(f2bf(v[j].y));
        float c = bf2f(f2bf(v[j].z)), d = bf2f(f2bf(v[j].w));
        ss += a * a + b * b + c * c + d * d;
    }
#pragma unroll
    for (int s = 1; s < 64; s <<= 1) ss += __shfl_xor(ss, s);
    float rs = 1.0f / (sqrtf(ss) + 1e-8f);
    uint2* dst = (uint2*)(rbf + (size_t)row * D_DIM);
#pragma unroll
    for (int j = 0; j < 4; j++) {
        uint2 o;
        o.x = pack2(v[j].x, v[j].y, rs);
        o.y = pack2(v[j].z, v[j].w, rs);
        dst[j * 64 + lane] = o;
    }
}

// ---------------- w_write row norms (fallback path) ---------------------------
__global__ __launch_bounds__(256) void k_sw(const float* __restrict__ ww, float* sw) {
    int t = threadIdx.x, lane = t & 63, wv = t >> 6;
    int row = blockIdx.x * 4 + wv;
    const float4* src = (const float4*)(ww + (size_t)row * D_DIM);
    float ss = 0.f;
#pragma unroll
    for (int j = 0; j < 4; j++) {
        float4 v = src[j * 64 + lane];
        float a = bf2f(f2bf(v.x)), b = bf2f(f2bf(v.y));
        float c = bf2f(f2bf(v.z)), d = bf2f(f2bf(v.w));
        ss += a * a + b * b + c * c + d * d;
    }
#pragma unroll
    for (int s = 1; s < 64; s <<= 1) ss += __shfl_xor(ss, s);
    if (lane == 0) sw[row] = 1.0f / (sqrtf(ss) + 1e-8f);
}

// ---------------- transpose w_write -> wwT[d][k] bf16 ------------------------
__global__ __launch_bounds__(256) void k_tww(const float* __restrict__ ww,
                                             const float* __restrict__ sw,
                                             int cbase, u16* __restrict__ wwT, int dstr) {
    __shared__ u16 tile[64][80];
    int kt = blockIdx.x * 64;
    int dt = blockIdx.y * 64;
    int t = threadIdx.x;
    int kk = t >> 4;
    int dd = (t & 15) * 4;
#pragma unroll
    for (int i = 0; i < 4; i++) {
        int krow = kk + i * 16;
        int kg = cbase + kt + krow;
        float s = sw[kg];
        float4 v = *(const float4*)(ww + (size_t)kg * D_DIM + dt + dd);
        tile[dd + 0][krow] = f2bf(v.x * s);
        tile[dd + 1][krow] = f2bf(v.y * s);
        tile[dd + 2][krow] = f2bf(v.z * s);
        tile[dd + 3][krow] = f2bf(v.w * s);
    }
    __syncthreads();
    int dd2 = t >> 2;
    int kk2 = (t & 3) * 16;
    uint4 o0 = *(const uint4*)&tile[dd2][kk2];
    uint4 o1 = *(const uint4*)&tile[dd2][kk2 + 8];
    u16* dst = wwT + (size_t)(dt + dd2) * dstr + kt + kk2;
    *(uint4*)dst = o0;
    *(uint4*)(dst + 8) = o1;
}

// ---------------- pass 1: scores GEMM + stats + row-major sb ------------------
__global__ __launch_bounds__(256) void k_pass1(const u16* __restrict__ hb,
                                               const u16* __restrict__ ebf, int cbase,
                                               float* rowsum, float* rowsq, float* colsum,
                                               u16* __restrict__ sb, int sstr) {
    int bm = blockIdx.x, bn = blockIdx.y;
    GEMM128_BODY(hb, D_DIM, ebf, D_DIM, D_DIM)
    // column sums from fragments (bf16-rounded values)
    float csv[4] = {0.f, 0.f, 0.f, 0.f};
#pragma unroll
    for (int m = 0; m < 4; m++)
#pragma unroll
        for (int rr = 0; rr < 4; rr++)
#pragma unroll
            for (int n = 0; n < 4; n++) csv[n] += bf2f(f2bf(acc[m][n][rr]));
#pragma unroll
    for (int n = 0; n < 4; n++) {
        float cv = csv[n];
        cv += __shfl_xor(cv, 16);
        cv += __shfl_xor(cv, 32);
        if (lg == 0) {
            int ng = cbase + bn * 128 + wc * 64 + n * 16 + l15;
            atomicAdd(&colsum[ng], cv);
        }
    }
    // restage full tile once; row stats + coalesced sb store in two passes
    RESTAGE_TO_LDS(f2bf(acc[m][n][rr]))
    int row_ = t >> 2, c0_ = (t & 3) * 32;
#pragma unroll
    for (int p = 0; p < 2; p++) {
        int lrow = p * 64 + row_;
        int grow = bm * 128 + lrow;
        float rs = 0.f, rq = 0.f;
        u16* dst = sb ? (sb + (size_t)grow * sstr + cbase + bn * 128 + c0_) : (u16*)nullptr;
#pragma unroll
        for (int j = 0; j < 4; j++) {
            u16x8 v = *(const u16x8*)&LDS[lrow * 136 + c0_ + j * 8];
            if (dst) *(u16x8*)(dst + j * 8) = v;
#pragma unroll
            for (int q = 0; q < 8; q++) {
                float sv = bf2f(v[q]);
                rs += sv;
                rq += sv * sv;
            }
        }
        rs += __shfl_xor(rs, 1);
        rq += __shfl_xor(rq, 1);
        rs += __shfl_xor(rs, 2);
        rq += __shfl_xor(rq, 2);
        if ((lane & 3) == 0) {
            atomicAdd(&rowsum[grow], rs);
            atomicAdd(&rowsq[grow], rq);
        }
    }
}

// ---------------- ns stats reduce -------------------------------------------
__global__ __launch_bounds__(256) void k_ns(const float* __restrict__ colsum, float* scal) {
    int i = blockIdx.x * 256 + threadIdx.x;
    float pm = colsum[i] * (1.0f / 4096.0f);
    float s1 = pm, s2 = pm * pm;
#pragma unroll
    for (int x = 1; x < 64; x <<= 1) {
        s1 += __shfl_xor(s1, x);
        s2 += __shfl_xor(s2, x);
    }
    __shared__ float sh[2][4];
    int w = threadIdx.x >> 6;
    if ((threadIdx.x & 63) == 0) { sh[0][w] = s1; sh[1][w] = s2; }
    __syncthreads();
    if (threadIdx.x == 0) {
        atomicAdd(&scal[0], sh[0][0] + sh[0][1] + sh[0][2] + sh[0][3]);
        atomicAdd(&scal[1], sh[1][0] + sh[1][1] + sh[1][2] + sh[1][3]);
    }
}

// ---------------- tau --------------------------------------------------------
__global__ __launch_bounds__(256) void k_tau(const float* __restrict__ rowsum,
                                             const float* __restrict__ rowsq,
                                             const float* __restrict__ tau_off,
                                             float* tau, float* invstd, float* smean, float* sstd) {
    int i = blockIdx.x * 256 + threadIdx.x;
    float sm = rowsum[i] * (1.0f / 32768.0f);
    float var = rowsq[i] * (1.0f / 32768.0f) - sm * sm;
    float sd = sqrtf(var) + 1e-8f;
    smean[i] = sm;
    sstd[i] = sd;
    invstd[i] = 1.0f / sd;
    tau[i] = sm + tau_off[i] * sd;
}

// ---------------- flow A: xr GEMM + gate, P in-place into sb ------------------
__global__ __launch_bounds__(256) void k_xr_gate_all(const u16* __restrict__ xb,
                                                     const u16* __restrict__ rbf,
                                                     u16* __restrict__ sbP,
                                                     const float* __restrict__ tau,
                                                     const float* __restrict__ invstd,
                                                     float* twc, float* act) {
    int bm = blockIdx.x, bn = blockIdx.y;
    const int tt = threadIdx.x;
    const int prow = tt >> 2, pc0 = (tt & 3) * 32;
    u16x8 sv_pre[2][4];
#pragma unroll
    for (int p = 0; p < 2; p++) {
        int grow = bm * 128 + p * 64 + prow;
        const u16* src = sbP + (size_t)grow * N_NEUR + bn * 128 + pc0;
#pragma unroll
        for (int j = 0; j < 4; j++) sv_pre[p][j] = *(const u16x8*)(src + j * 8);
    }
    GEMM128_BODY(xb, D_DIM, rbf, D_DIM, D_DIM)
    RESTAGE_TO_LDS(f2bf(acc[m][n][rr]))
#pragma unroll
    for (int p = 0; p < 2; p++) {
        int lrow = p * 64 + prow;
        int grow = bm * 128 + lrow;
        float tl = tau[grow], il = invstd[grow];
        float wsum = 0.f, cnt = 0.f;
        u16* gptr = sbP + (size_t)grow * N_NEUR + bn * 128 + pc0;
#pragma unroll
        for (int j = 0; j < 4; j++) {
            u16x8 xr8 = *(const u16x8*)&LDS[lrow * 136 + pc0 + j * 8];
            u16x8 sv8 = sv_pre[p][j];
            u16x8 o;
#pragma unroll
            for (int q = 0; q < 8; q++) {
                float xf = bf2f(xr8[q]);
                float raw = bf2f(sv8[q]) - tl;
                float sig = 1.0f / (1.0f + __expf(-raw * il));
                bool g = raw > 0.0f;
                wsum += sig * xf * xf;
                cnt += g ? 1.0f : 0.0f;
                o[q] = g ? xr8[q] : (u16)0;
            }
            *(u16x8*)(gptr + j * 8) = o;
        }
        wsum += __shfl_xor(wsum, 1);
        cnt += __shfl_xor(cnt, 1);
        wsum += __shfl_xor(wsum, 2);
        cnt += __shfl_xor(cnt, 2);
        if ((lane & 3) == 0) {
            atomicAdd(&twc[grow], wsum);
            atomicAdd(&act[grow], cnt);
        }
    }
}

// ---------------- flow A: all-chunk write GEMM -> bf16 partials --------------
__global__ __launch_bounds__(256) void k_pass2b_all(const u16* __restrict__ sbP,
                                                    const u16* __restrict__ wwT,
                                                    u16* __restrict__ part) {
    int bm = blockIdx.x;
    int bn = blockIdx.y;
    int zz = blockIdx.z;
    const u16* Pz = sbP + (size_t)zz * CS;
    const u16* Wz = wwT + (size_t)zz * CS;
    u16* pz = part + (size_t)zz * M_TOT * D_DIM;
    GEMM128_BODY(Pz, N_NEUR, Wz, N_NEUR, CS)
    RESTAGE_U16_TILE(f2bf(acc[m][n][rr]), pz, D_DIM, bn * 128)
}

// ---------------- final: sum bf16 partials, normalize, per-row outputs -------
__global__ __launch_bounds__(256) void k_norm_comb(const u16* __restrict__ part,
                                                   const float* __restrict__ twc,
                                                   const float* __restrict__ act,
                                                   float* __restrict__ out0,
                                                   float* out1, float* out2) {
    int row = blockIdx.x;
    float den = sqrtf(twc[row] + 1e-6f);
    den = fmaxf(den, 0.001f);
    float inv = 1.0f / den;
    size_t base = (size_t)row * D_DIM + threadIdx.x * 4;
    float s0 = 0.f, s1 = 0.f, s2 = 0.f, s3 = 0.f;
#pragma unroll
    for (int c = 0; c < NCHUNK; c++) {
        u16x4 v = *(const u16x4*)(part + (size_t)c * M_TOT * D_DIM + base);
        s0 += bf2f(v[0]);
        s1 += bf2f(v[1]);
        s2 += bf2f(v[2]);
        s3 += bf2f(v[3]);
    }
    float4 o;
    o.x = bf2f(f2bf(s0 * inv));
    o.y = bf2f(f2bf(s1 * inv));
    o.z = bf2f(f2bf(s2 * inv));
    o.w = bf2f(f2bf(s3 * inv));
    *(float4*)(out0 + base) = o;
    if (threadIdx.x == 0) {
        out1[row] = act[row] * (1.0f / 32768.0f);
        out2[row] = act[row] > 0.0f ? 1.0f : 0.0f;
    }
}

// ---------------- flow B kernels (compact fallback) ---------------------------
__global__ __launch_bounds__(256) void k_xr_plain(const u16* __restrict__ xb,
                                                  const u16* __restrict__ rbf,
                                                  u16* __restrict__ P) {
    int bm = blockIdx.x, bn = blockIdx.y;
    GEMM128_BODY(xb, D_DIM, rbf, D_DIM, D_DIM)
    RESTAGE_U16_TILE(f2bf(acc[m][n][rr]), P, CS, bn * 128)
}

__global__ __launch_bounds__(256) void k_gate_gemm(const u16* __restrict__ hb,
                                                   const u16* __restrict__ ebf,
                                                   const float* __restrict__ tau,
                                                   const float* __restrict__ invstd,
                                                   u16* __restrict__ P, float* twc, float* act) {
    int bm = blockIdx.x, bn = blockIdx.y;
    GEMM128_BODY(hb, D_DIM, ebf, D_DIM, D_DIM)
#pragma unroll
    for (int m = 0; m < 4; m++) {
#pragma unroll
        for (int rr = 0; rr < 4; rr++) {
            int mg = bm * 128 + wr * 64 + m * 16 + lg * 4 + rr;
            float tl = tau[mg], il = invstd[mg];
            float wsum = 0.f, cnt = 0.f;
#pragma unroll
            for (int n = 0; n < 4; n++) {
                int ngl = bn * 128 + wc * 64 + n * 16 + l15;
                float sv = bf2f(f2bf(acc[m][n][rr]));
                float raw = sv - tl;
                u16 xrb = P[(size_t)mg * CS + ngl];
                float xf = bf2f(xrb);
                float sig = 1.0f / (1.0f + __expf(-raw * il));
                bool g = raw > 0.0f;
                wsum += sig * xf * xf;
                cnt += g ? 1.0f : 0.0f;
                P[(size_t)mg * CS + ngl] = g ? xrb : (u16)0;
            }
#pragma unroll
            for (int x = 1; x < 16; x <<= 1) {
                wsum += __shfl_xor(wsum, x);
                cnt += __shfl_xor(cnt, x);
            }
            if (l15 == 0) {
                atomicAdd(&twc[mg], wsum);
                atomicAdd(&act[mg], cnt);
            }
        }
    }
}

__global__ __launch_bounds__(256) void k_pass2b(const u16* __restrict__ P,
                                                const u16* __restrict__ wwT, int bstr,
                                                float* __restrict__ out) {
    int bm = blockIdx.x;
    int bn = blockIdx.y;
    GEMM128_BODY(P, CS, wwT, bstr, CS)
#pragma unroll
    for (int m = 0; m < 4; m++)
#pragma unroll
        for (int n = 0; n < 4; n++)
#pragma unroll
            for (int rr = 0; rr < 4; rr++) {
                int mg = bm * 128 + wr * 64 + m * 16 + lg * 4 + rr;
                int dg = bn * 128 + wc * 64 + n * 16 + l15;
                out[(size_t)mg * D_DIM + dg] += bf2f(f2bf(acc[m][n][rr]));
            }
}

__global__ __launch_bounds__(256) void k_norm_f(float* __restrict__ out,
                                                const float* __restrict__ twc,
                                                const float* __restrict__ act,
                                                float* out1, float* out2) {
    int row = blockIdx.x;
    float den = sqrtf(twc[row] + 1e-6f);
    den = fmaxf(den, 0.001f);
    float inv = 1.0f / den;
    float* p = out + (size_t)row * D_DIM;
    int i = threadIdx.x * 4;
    float4 v = *(float4*)(p + i);
    v.x = bf2f(f2bf(v.x * inv));
    v.y = bf2f(f2bf(v.y * inv));
    v.z = bf2f(f2bf(v.z * inv));
    v.w = bf2f(f2bf(v.w * inv));
    *(float4*)(p + i) = v;
    if (threadIdx.x == 0) {
        out1[row] = act[row] * (1.0f / 32768.0f);
        out2[row] = act[row] > 0.0f ? 1.0f : 0.0f;
    }
}

// ---------------- scalar outputs ---------------------------------------------
__global__ __launch_bounds__(256) void k_scalars(const float* __restrict__ smean,
                                                 const float* __restrict__ sstd,
                                                 const float* __restrict__ twc,
                                                 const float* __restrict__ act,
                                                 const float* __restrict__ scal,
                                                 float* outS) {
    float a = 0.f, b = 0.f, c = 0.f, d = 0.f;
    for (int i = threadIdx.x; i < 4096; i += 256) {
        a += smean[i];
        b += sstd[i];
        c += twc[i];
        d += act[i];
    }
#pragma unroll
    for (int x = 1; x < 64; x <<= 1) {
        a += __shfl_xor(a, x);
        b += __shfl_xor(b, x);
        c += __shfl_xor(c, x);
        d += __shfl_xor(d, x);
    }
    __shared__ float sh[4][4];
    int w = threadIdx.x >> 6;
    if ((threadIdx.x & 63) == 0) { sh[0][w] = a; sh[1][w] = b; sh[2][w] = c; sh[3][w] = d; }
    __syncthreads();
    if (threadIdx.x == 0) {
        float ma = sh[0][0] + sh[0][1] + sh[0][2] + sh[0][3];
        float mb = sh[1][0] + sh[1][1] + sh[1][2] + sh[1][3];
        float mc = sh[2][0] + sh[2][1] + sh[2][2] + sh[2][3];
        float md = sh[3][0] + sh[3][1] + sh[3][2] + sh[3][3];
        float mean_score = scal[0] * (1.0f / 32768.0f);
        float var_score = scal[1] * (1.0f / 32768.0f) - mean_score * mean_score;
        outS[0] = var_score / (mean_score * mean_score + var_score + 0.01f);  // score_lb
        outS[1] = mb * (1.0f / 4096.0f);                                      // score_std_out
        outS[2] = mc * (1.0f / 4096.0f);                                      // es_out
        outS[3] = md * (1.0f / 4096.0f);                                      // active_n_mean
        outS[4] = ma * (1.0f / 4096.0f);                                      // score_mean_out
    }
}

// ---------------- workspace layout (bytes) -----------------------------------
static constexpr size_t OFF_HB     = 0;           // 8 MB
static constexpr size_t OFF_XB     = 8388608;     // 8 MB
static constexpr size_t OFF_P      = 16777216;    // 32 MB (fallback only)
static constexpr size_t OFF_EBF    = 50331648;    // 64 MB; part (64 MB bf16) overlays
static constexpr size_t OFF_RBF    = 117440512;   // 64 MB
static constexpr size_t OFF_WWT    = 184549376;   // 64 MB  [D][N] (flow A) / [D][CS] fallback
static constexpr size_t OFF_SW     = 251658240;   // 128 KB
static constexpr size_t OFF_ROWSUM = 251789312;
static constexpr size_t OFF_ROWSQ  = 251805696;
static constexpr size_t OFF_COLSUM = 251822080;   // 128 KB
static constexpr size_t OFF_TAU    = 251953152;
static constexpr size_t OFF_INVSTD = 251969536;
static constexpr size_t OFF_SMEAN  = 251985920;
static constexpr size_t OFF_SSTD   = 252002304;
static constexpr size_t OFF_TWC    = 252018688;
static constexpr size_t OFF_ACT    = 252035072;
static constexpr size_t OFF_SCAL   = 252051456;
static constexpr size_t STATS_END  = 252051520;
static constexpr size_t ZERO_LEN   = STATS_END - OFF_ROWSUM;
static constexpr size_t OFF_SB     = 252706816;   // 256 MB (flow A) scores -> gated P
static constexpr size_t FULL_END   = OFF_SB + (size_t)M_TOT * N_NEUR * 2;  // ~497 MB
static constexpr size_t OFF_PART   = OFF_EBF;     // 64 MB bf16 partials overlay

extern "C" void kernel_launch(void* const* d_in, const int* in_sizes, int n_in,
                              void* d_out, int out_size, void* d_ws, size_t ws_size,
                              hipStream_t stream) {
    const float* x = (const float*)d_in[0];
    const float* h = (const float*)d_in[1];
    const float* emb = (const float*)d_in[2];
    const float* tau_off = (const float*)d_in[3];
    const float* w_read = (const float*)d_in[4];
    const float* w_write = (const float*)d_in[5];
    char* ws = (char*)d_ws;
    u16* hb = (u16*)(ws + OFF_HB);
    u16* xb = (u16*)(ws + OFF_XB);
    u16* P = (u16*)(ws + OFF_P);
    u16* ebf = (u16*)(ws + OFF_EBF);
    u16* rbf = (u16*)(ws + OFF_RBF);
    u16* wwT = (u16*)(ws + OFF_WWT);
    float* sw = (float*)(ws + OFF_SW);
    float* rowsum = (float*)(ws + OFF_ROWSUM);
    float* rowsq = (float*)(ws + OFF_ROWSQ);
    float* colsum = (float*)(ws + OFF_COLSUM);
    float* tau = (float*)(ws + OFF_TAU);
    float* invstd = (float*)(ws + OFF_INVSTD);
    float* smean = (float*)(ws + OFF_SMEAN);
    float* sstd = (float*)(ws + OFF_SSTD);
    float* twc = (float*)(ws + OFF_TWC);
    float* act = (float*)(ws + OFF_ACT);
    float* scal = (float*)(ws + OFF_SCAL);
    u16* part = (u16*)(ws + OFF_PART);
    const bool fullA = ws_size >= FULL_END;
    u16* sbP = fullA ? (u16*)(ws + OFF_SB) : (u16*)nullptr;

    float* out0 = (float*)d_out;
    float* out1 = out0 + (size_t)M_TOT * D_DIM;
    float* out2 = out1 + M_TOT;
    float* outS = out2 + M_TOT;

    hipMemsetAsync(ws + OFF_ROWSUM, 0, ZERO_LEN, stream);

    k_cvt<<<4096, 256, 0, stream>>>(h, x, hb, xb);

    if (fullA) {
        k_cvt_ern3<<<dim3(N_NEUR / 4, 3), 256, 0, stream>>>(emb, w_read, w_write,
                                                            ebf, rbf, sw);
        k_tww<<<dim3(N_NEUR / 64, 16), 256, 0, stream>>>(w_write, sw, 0, wwT, N_NEUR);
        k_pass1<<<dim3(32, 256), 256, 0, stream>>>(hb, ebf, 0, rowsum, rowsq, colsum,
                                                   sbP, N_NEUR);
        k_ns<<<128, 256, 0, stream>>>(colsum, scal);
        k_tau<<<16, 256, 0, stream>>>(rowsum, rowsq, tau_off, tau, invstd, smean, sstd);
        k_xr_gate_all<<<dim3(32, 256), 256, 0, stream>>>(xb, rbf, sbP, tau, invstd, twc, act);
        k_pass2b_all<<<dim3(32, 8, 8), 256, 0, stream>>>(sbP, wwT, part);
        k_norm_comb<<<4096, 256, 0, stream>>>(part, twc, act, out0, out1, out2);
    } else {
        hipMemsetAsync(d_out, 0, (size_t)M_TOT * D_DIM * 4, stream);
        k_sw<<<N_NEUR / 4, 256, 0, stream>>>(w_write, sw);
        for (int c = 0; c < NCHUNK; c++) {
            k_cvt_e_norm<<<CS / 4, 256, 0, stream>>>(emb, c * CS, ebf);
            k_pass1<<<dim3(32, 32), 256, 0, stream>>>(hb, ebf, c * CS, rowsum, rowsq, colsum,
                                                      (u16*)nullptr, 0);
        }
        k_ns<<<128, 256, 0, stream>>>(colsum, scal);
        k_tau<<<16, 256, 0, stream>>>(rowsum, rowsq, tau_off, tau, invstd, smean, sstd);
        for (int c = 0; c < NCHUNK; c++) {
            k_cvt_e_norm<<<CS / 4, 256, 0, stream>>>(emb, c * CS, ebf);
            k_cvt_r_norm<<<CS / 4, 256, 0, stream>>>(w_read, c * CS, rbf);
            k_tww<<<dim3(CS / 64, 16), 256, 0, stream>>>(w_write, sw, c * CS, wwT, CS);
            k_xr_plain<<<dim3(32, 32), 256, 0, stream>>>(xb, rbf, P);
            k_gate_gemm<<<dim3(32, 32), 256, 0, stream>>>(hb, ebf, tau, invstd, P, twc, act);
            k_pass2b<<<dim3(32, 8), 256, 0, stream>>>(P, wwT, CS, out0);
        }
        k_norm_f<<<4096, 256, 0, stream>>>(out0, twc, act, out1, out2);
    }
    k_scalars<<<1, 256, 0, stream>>>(smean, sstd, twc, act, scal, outS);
}

// Round 17
// 1402.308 us; speedup vs baseline: 1.3190x; 1.0557x over previous
//
#include <hip/hip_runtime.h>
#include <stdint.h>

// Problem constants (B=4,S=1024,D=1024,N=32768,n_chunks=8)
#define M_TOT 4096
#define D_DIM 1024
#define N_NEUR 32768
#define NCHUNK 8
#define CS 4096

typedef float f32x4 __attribute__((ext_vector_type(4)));
typedef __bf16 bf16x8 __attribute__((ext_vector_type(8)));
typedef unsigned short u16;
typedef unsigned int u32;
typedef u16 u16x8 __attribute__((ext_vector_type(8)));
typedef u16 u16x4 __attribute__((ext_vector_type(4)));

__device__ __forceinline__ u16 f2bf(float f) {
    u32 u = __builtin_bit_cast(u32, f);
    u = (u + 0x7FFFu + ((u >> 16) & 1u)) >> 16;
    return (u16)u;
}
__device__ __forceinline__ float bf2f(u16 h) {
    u32 u = ((u32)h) << 16;
    return __builtin_bit_cast(float, u);
}
__device__ __forceinline__ u32 pack2(float a, float b, float s) {
    return (u32)f2bf(a * s) | ((u32)f2bf(b * s) << 16);
}

typedef __attribute__((address_space(1))) const u32 as1_u32;
typedef __attribute__((address_space(3))) u32 as3_u32;
__device__ __forceinline__ void gload16(const void* g, void* l) {
    __builtin_amdgcn_global_load_lds((as1_u32*)g, (as3_u32*)l, 16, 0, 0);
}

#define MFMA(a, b, c) __builtin_amdgcn_mfma_f32_16x16x32_bf16((a), (b), (c), 0, 0, 0)

// 128x128-tile bf16 GEMM main loop, depth-3 pipelined (T4 counted vmcnt):
// triple-buffered LDS; at iter i issue tile i+2's 4 global_load_lds, then
// s_waitcnt vmcnt(8) (tiles i+1,i+2 stay in flight; tile i proven complete),
// raw s_barrier, ds_read+MFMA on buf[i%3], s_barrier. Tail: vmcnt(4) then
// vmcnt(0). Race-freedom: buffer written at iter i is buf[(i-1)%3]; all its
// readers passed iter i-1's closing barrier before any wave issues at iter i.
// Depth-2 (R16) verified this barrier pattern and won -8% on xr_gate; depth-3
// extends latency cover from ~1 K-step (~350cy, covers L2) to ~2 (~700cy,
// covers most of HBM's ~900cy).
// LDS[24576] u16 (48 KB): buf k at [k*8192, k*8192+8192) = A|B halves.
// Epilogue restage reuses [0,17408) as 128 rows x stride 136.
// (R13: BK=64 regressed. R14: XCD bn-swizzle regressed. Keep BK=32, linear.)
#define GEMM128_BODY(ABASE, ASTR, BBASE, BSTR, KLEN)                                  \
    __shared__ u16 LDS[24576];                                                        \
    const int t = threadIdx.x, lane = t & 63, w = t >> 6;                             \
    const int wr = w >> 1, wc = w & 1, l15 = lane & 15, lg = lane >> 4;               \
    f32x4 acc[4][4] = {};                                                             \
    {                                                                                 \
        const int seg0 = w * 2;                                                       \
        const int rb = lane >> 2, cl = (lane & 3) * 8;                                \
        const size_t ro0 = (size_t)(seg0 * 16 + rb);                                  \
        const u16* pa0 = (ABASE) + ((size_t)bm * 128 + ro0) * (ASTR) + cl;            \
        const u16* pb0 = (BBASE) + ((size_t)bn * 128 + ro0) * (BSTR) + cl;            \
        const u16* pa1 = pa0 + (size_t)16 * (ASTR);                                   \
        const u16* pb1 = pb0 + (size_t)16 * (BSTR);                                   \
        gload16(pa0, LDS + seg0 * 512);                                               \
        gload16(pa1, LDS + seg0 * 512 + 512);                                         \
        gload16(pb0, LDS + 4096 + seg0 * 512);                                        \
        gload16(pb1, LDS + 4096 + seg0 * 512 + 512);                                  \
        if (32 < (KLEN)) {                                                            \
            gload16(pa0 + 32, LDS + 8192 + seg0 * 512);                               \
            gload16(pa1 + 32, LDS + 8192 + seg0 * 512 + 512);                         \
            gload16(pb0 + 32, LDS + 12288 + seg0 * 512);                              \
            gload16(pb1 + 32, LDS + 12288 + seg0 * 512 + 512);                        \
        }                                                                             \
        int co = 0, no = 16384;                                                       \
        for (int k0 = 0; k0 < (KLEN); k0 += 32) {                                     \
            if (k0 + 64 < (KLEN)) {                                                   \
                gload16(pa0 + k0 + 64, LDS + no + seg0 * 512);                        \
                gload16(pa1 + k0 + 64, LDS + no + seg0 * 512 + 512);                  \
                gload16(pb0 + k0 + 64, LDS + no + 4096 + seg0 * 512);                 \
                gload16(pb1 + k0 + 64, LDS + no + 4096 + seg0 * 512 + 512);           \
                asm volatile("s_waitcnt vmcnt(8)" ::: "memory");                      \
            } else if (k0 + 32 < (KLEN)) {                                            \
                asm volatile("s_waitcnt vmcnt(4)" ::: "memory");                      \
            } else {                                                                  \
                asm volatile("s_waitcnt vmcnt(0)" ::: "memory");                      \
            }                                                                         \
            __builtin_amdgcn_s_barrier();                                             \
            bf16x8 afr[4], bfr[4];                                                    \
            _Pragma("unroll") for (int m = 0; m < 4; m++)                             \
                afr[m] = *(const bf16x8*)&LDS[co + (wr * 64 + m * 16 + l15) * 32 +    \
                                              lg * 8];                                \
            _Pragma("unroll") for (int n = 0; n < 4; n++)                             \
                bfr[n] = *(const bf16x8*)&LDS[co + 4096 +                             \
                                              (wc * 64 + n * 16 + l15) * 32 + lg * 8];\
            _Pragma("unroll") for (int m = 0; m < 4; m++)                             \
                _Pragma("unroll") for (int n = 0; n < 4; n++)                         \
                    acc[m][n] = MFMA(afr[m], bfr[n], acc[m][n]);                      \
            __builtin_amdgcn_s_barrier();                                             \
            co += 8192;                                                               \
            if (co == 24576) co = 0;                                                  \
            no += 8192;                                                               \
            if (no == 24576) no = 0;                                                  \
        }                                                                             \
    }

// Single-pass full-tile restage: fragments -> LDS[128 rows][stride 136].
#define RESTAGE_TO_LDS(VALS)                                                          \
    __syncthreads();                                                                  \
    _Pragma("unroll") for (int m = 0; m < 4; m++)                                     \
        _Pragma("unroll") for (int rr = 0; rr < 4; rr++)                              \
            _Pragma("unroll") for (int n = 0; n < 4; n++) {                           \
                int lrow = wr * 64 + m * 16 + lg * 4 + rr;                            \
                LDS[lrow * 136 + wc * 64 + n * 16 + l15] = (VALS);                    \
            }                                                                         \
    __syncthreads();

// Full-tile row-major u16 writeout via the single restage (two read passes).
#define RESTAGE_U16_TILE(VALS, DSTBASE, DSTSTRIDE, COLBASE)                           \
    {                                                                                 \
        RESTAGE_TO_LDS(VALS)                                                          \
        int row_ = t >> 2, c0_ = (t & 3) * 32;                                        \
        _Pragma("unroll") for (int p = 0; p < 2; p++) {                               \
            int lrow = p * 64 + row_;                                                 \
            u16* dst_ = (DSTBASE) + (size_t)(bm * 128 + lrow) * (DSTSTRIDE) +         \
                        (COLBASE) + c0_;                                              \
            const u16* srcl_ = &LDS[lrow * 136 + c0_];                                \
            _Pragma("unroll") for (int j = 0; j < 4; j++)                             \
                *(u16x8*)(dst_ + j * 8) = *(const u16x8*)(srcl_ + j * 8);             \
        }                                                                             \
    }

// ---------------- prep: h,x -> bf16 ----------------------------------------
__global__ __launch_bounds__(256) void k_cvt(const float* __restrict__ h,
                                             const float* __restrict__ x,
                                             u16* __restrict__ hb, u16* __restrict__ xb) {
    size_t i = ((size_t)blockIdx.x * 256 + threadIdx.x) * 4;
    float4 v = *(const float4*)(h + i);
    uint2 o;
    o.x = pack2(v.x, v.y, 1.0f);
    o.y = pack2(v.z, v.w, 1.0f);
    *(uint2*)(hb + i) = o;
    v = *(const float4*)(x + i);
    o.x = pack2(v.x, v.y, 1.0f);
    o.y = pack2(v.z, v.w, 1.0f);
    *(uint2*)(xb + i) = o;
}

// ---------------- fused norm+convert: y=0 emb->ebf, y=1 w_read->rbf, y=2 sw --
__global__ __launch_bounds__(256) void k_cvt_ern3(const float* __restrict__ emb,
                                                  const float* __restrict__ wrd,
                                                  const float* __restrict__ ww,
                                                  u16* __restrict__ ebf, u16* __restrict__ rbf,
                                                  float* __restrict__ sw) {
    int t = threadIdx.x, lane = t & 63, wv = t >> 6;
    int row = blockIdx.x * 4 + wv;
    int which = blockIdx.y;
    const float* srcm = which == 0 ? emb : (which == 1 ? wrd : ww);
    const float4* src = (const float4*)(srcm + (size_t)row * D_DIM);
    float4 v[4];
    float ss = 0.f;
#pragma unroll
    for (int j = 0; j < 4; j++) {
        v[j] = src[j * 64 + lane];
        if (which == 0) {
            ss += v[j].x * v[j].x + v[j].y * v[j].y + v[j].z * v[j].z + v[j].w * v[j].w;
        } else {
            float a = bf2f(f2bf(v[j].x)), b = bf2f(f2bf(v[j].y));
            float c = bf2f(f2bf(v[j].z)), d = bf2f(f2bf(v[j].w));
            ss += a * a + b * b + c * c + d * d;
        }
    }
#pragma unroll
    for (int s = 1; s < 64; s <<= 1) ss += __shfl_xor(ss, s);
    float sc = 1.0f / (sqrtf(ss) + 1e-8f);
    if (which == 2) {
        if (lane == 0) sw[row] = sc;
        return;
    }
    uint2* dst = (uint2*)((which == 0 ? ebf : rbf) + (size_t)row * D_DIM);
#pragma unroll
    for (int j = 0; j < 4; j++) {
        uint2 o;
        o.x = pack2(v[j].x, v[j].y, sc);
        o.y = pack2(v[j].z, v[j].w, sc);
        dst[j * 64 + lane] = o;
    }
}

// per-chunk variants for the compact fallback path
__global__ __launch_bounds__(256) void k_cvt_e_norm(const float* __restrict__ emb,
                                                    int cbase, u16* __restrict__ ebf) {
    int t = threadIdx.x, lane = t & 63, wv = t >> 6;
    int row = blockIdx.x * 4 + wv;
    const float4* src = (const float4*)(emb + (size_t)(cbase + row) * D_DIM);
    float4 v[4];
    float ss = 0.f;
#pragma unroll
    for (int j = 0; j < 4; j++) {
        v[j] = src[j * 64 + lane];
        ss += v[j].x * v[j].x + v[j].y * v[j].y + v[j].z * v[j].z + v[j].w * v[j].w;
    }
#pragma unroll
    for (int s = 1; s < 64; s <<= 1) ss += __shfl_xor(ss, s);
    float es = 1.0f / (sqrtf(ss) + 1e-8f);
    uint2* dst = (uint2*)(ebf + (size_t)row * D_DIM);
#pragma unroll
    for (int j = 0; j < 4; j++) {
        uint2 o;
        o.x = pack2(v[j].x, v[j].y, es);
        o.y = pack2(v[j].z, v[j].w, es);
        dst[j * 64 + lane] = o;
    }
}

__global__ __launch_bounds__(256) void k_cvt_r_norm(const float* __restrict__ wrd,
                                                    int cbase, u16* __restrict__ rbf) {
    int t = threadIdx.x, lane = t & 63, wv = t >> 6;
    int row = blockIdx.x * 4 + wv;
    const float4* src = (const float4*)(wrd + (size_t)(cbase + row) * D_DIM);
    float4 v[4];
    float ss = 0.f;
#pragma unroll
    for (int j = 0; j < 4; j++) {
        v[j] = src[j * 64 + lane];
        float a = bf2f(f2bf(v[j].x)), b = bf2f(f2bf(v[j].y));
        float c = bf2f(f2bf(v[j].z)), d = bf2f(f2bf(v[j].w));
        ss += a * a + b * b + c * c + d * d;
    }
#pragma unroll
    for (int s = 1; s < 64; s <<= 1) ss += __shfl_xor(ss, s);
    float rs = 1.0f / (sqrtf(ss) + 1e-8f);
    uint2* dst = (uint2*)(rbf + (size_t)row * D_DIM);
#pragma unroll
    for (int j = 0; j < 4; j++) {
        uint2 o;
        o.x = pack2(v[j].x, v[j].y, rs);
        o.y = pack2(v[j].z, v[j].w, rs);
        dst[j * 64 + lane] = o;
    }
}

// ---------------- w_write row norms (fallback path) ---------------------------
__global__ __launch_bounds__(256) void k_sw(const float* __restrict__ ww, float* sw) {
    int t = threadIdx.x, lane = t & 63, wv = t >> 6;
    int row = blockIdx.x * 4 + wv;
    const float4* src = (const float4*)(ww + (size_t)row * D_DIM);
    float ss = 0.f;
#pragma unroll
    for (int j = 0; j < 4; j++) {
        float4 v = src[j * 64 + lane];
        float a = bf2f(f2bf(v.x)), b = bf2f(f2bf(v.y));
        float c = bf2f(f2bf(v.z)), d = bf2f(f2bf(v.w));
        ss += a * a + b * b + c * c + d * d;
    }
#pragma unroll
    for (int s = 1; s < 64; s <<= 1) ss += __shfl_xor(ss, s);
    if (lane == 0) sw[row] = 1.0f / (sqrtf(ss) + 1e-8f);
}

// ---------------- transpose w_write -> wwT[d][k] bf16 ------------------------
__global__ __launch_bounds__(256) void k_tww(const float* __restrict__ ww,
                                             const float* __restrict__ sw,
                                             int cbase, u16* __restrict__ wwT, int dstr) {
    __shared__ u16 tile[64][80];
    int kt = blockIdx.x * 64;
    int dt = blockIdx.y * 64;
    int t = threadIdx.x;
    int kk = t >> 4;
    int dd = (t & 15) * 4;
#pragma unroll
    for (int i = 0; i < 4; i++) {
        int krow = kk + i * 16;
        int kg = cbase + kt + krow;
        float s = sw[kg];
        float4 v = *(const float4*)(ww + (size_t)kg * D_DIM + dt + dd);
        tile[dd + 0][krow] = f2bf(v.x * s);
        tile[dd + 1][krow] = f2bf(v.y * s);
        tile[dd + 2][krow] = f2bf(v.z * s);
        tile[dd + 3][krow] = f2bf(v.w * s);
    }
    __syncthreads();
    int dd2 = t >> 2;
    int kk2 = (t & 3) * 16;
    uint4 o0 = *(const uint4*)&tile[dd2][kk2];
    uint4 o1 = *(const uint4*)&tile[dd2][kk2 + 8];
    u16* dst = wwT + (size_t)(dt + dd2) * dstr + kt + kk2;
    *(uint4*)dst = o0;
    *(uint4*)(dst + 8) = o1;
}

// ---------------- pass 1: scores GEMM + stats + row-major sb ------------------
__global__ __launch_bounds__(256) void k_pass1(const u16* __restrict__ hb,
                                               const u16* __restrict__ ebf, int cbase,
                                               float* rowsum, float* rowsq, float* colsum,
                                               u16* __restrict__ sb, int sstr) {
    int bm = blockIdx.x, bn = blockIdx.y;
    GEMM128_BODY(hb, D_DIM, ebf, D_DIM, D_DIM)
    // column sums from fragments (bf16-rounded values)
    float csv[4] = {0.f, 0.f, 0.f, 0.f};
#pragma unroll
    for (int m = 0; m < 4; m++)
#pragma unroll
        for (int rr = 0; rr < 4; rr++)
#pragma unroll
            for (int n = 0; n < 4; n++) csv[n] += bf2f(f2bf(acc[m][n][rr]));
#pragma unroll
    for (int n = 0; n < 4; n++) {
        float cv = csv[n];
        cv += __shfl_xor(cv, 16);
        cv += __shfl_xor(cv, 32);
        if (lg == 0) {
            int ng = cbase + bn * 128 + wc * 64 + n * 16 + l15;
            atomicAdd(&colsum[ng], cv);
        }
    }
    // restage full tile once; row stats + coalesced sb store in two passes
    RESTAGE_TO_LDS(f2bf(acc[m][n][rr]))
    int row_ = t >> 2, c0_ = (t & 3) * 32;
#pragma unroll
    for (int p = 0; p < 2; p++) {
        int lrow = p * 64 + row_;
        int grow = bm * 128 + lrow;
        float rs = 0.f, rq = 0.f;
        u16* dst = sb ? (sb + (size_t)grow * sstr + cbase + bn * 128 + c0_) : (u16*)nullptr;
#pragma unroll
        for (int j = 0; j < 4; j++) {
            u16x8 v = *(const u16x8*)&LDS[lrow * 136 + c0_ + j * 8];
            if (dst) *(u16x8*)(dst + j * 8) = v;
#pragma unroll
            for (int q = 0; q < 8; q++) {
                float sv = bf2f(v[q]);
                rs += sv;
                rq += sv * sv;
            }
        }
        rs += __shfl_xor(rs, 1);
        rq += __shfl_xor(rq, 1);
        rs += __shfl_xor(rs, 2);
        rq += __shfl_xor(rq, 2);
        if ((lane & 3) == 0) {
            atomicAdd(&rowsum[grow], rs);
            atomicAdd(&rowsq[grow], rq);
        }
    }
}

// ---------------- ns stats reduce -------------------------------------------
__global__ __launch_bounds__(256) void k_ns(const float* __restrict__ colsum, float* scal) {
    int i = blockIdx.x * 256 + threadIdx.x;
    float pm = colsum[i] * (1.0f / 4096.0f);
    float s1 = pm, s2 = pm * pm;
#pragma unroll
    for (int x = 1; x < 64; x <<= 1) {
        s1 += __shfl_xor(s1, x);
        s2 += __shfl_xor(s2, x);
    }
    __shared__ float sh[2][4];
    int w = threadIdx.x >> 6;
    if ((threadIdx.x & 63) == 0) { sh[0][w] = s1; sh[1][w] = s2; }
    __syncthreads();
    if (threadIdx.x == 0) {
        atomicAdd(&scal[0], sh[0][0] + sh[0][1] + sh[0][2] + sh[0][3]);
        atomicAdd(&scal[1], sh[1][0] + sh[1][1] + sh[1][2] + sh[1][3]);
    }
}

// ---------------- tau --------------------------------------------------------
__global__ __launch_bounds__(256) void k_tau(const float* __restrict__ rowsum,
                                             const float* __restrict__ rowsq,
                                             const float* __restrict__ tau_off,
                                             float* tau, float* invstd, float* smean, float* sstd) {
    int i = blockIdx.x * 256 + threadIdx.x;
    float sm = rowsum[i] * (1.0f / 32768.0f);
    float var = rowsq[i] * (1.0f / 32768.0f) - sm * sm;
    float sd = sqrtf(var) + 1e-8f;
    smean[i] = sm;
    sstd[i] = sd;
    invstd[i] = 1.0f / sd;
    tau[i] = sm + tau_off[i] * sd;
}

// ---------------- flow A: xr GEMM + gate, P in-place into sb ------------------
__global__ __launch_bounds__(256) void k_xr_gate_all(const u16* __restrict__ xb,
                                                     const u16* __restrict__ rbf,
                                                     u16* __restrict__ sbP,
                                                     const float* __restrict__ tau,
                                                     const float* __restrict__ invstd,
                                                     float* twc, float* act) {
    int bm = blockIdx.x, bn = blockIdx.y;
    const int tt = threadIdx.x;
    const int prow = tt >> 2, pc0 = (tt & 3) * 32;
    u16x8 sv_pre[2][4];
#pragma unroll
    for (int p = 0; p < 2; p++) {
        int grow = bm * 128 + p * 64 + prow;
        const u16* src = sbP + (size_t)grow * N_NEUR + bn * 128 + pc0;
#pragma unroll
        for (int j = 0; j < 4; j++) sv_pre[p][j] = *(const u16x8*)(src + j * 8);
    }
    GEMM128_BODY(xb, D_DIM, rbf, D_DIM, D_DIM)
    RESTAGE_TO_LDS(f2bf(acc[m][n][rr]))
#pragma unroll
    for (int p = 0; p < 2; p++) {
        int lrow = p * 64 + prow;
        int grow = bm * 128 + lrow;
        float tl = tau[grow], il = invstd[grow];
        float wsum = 0.f, cnt = 0.f;
        u16* gptr = sbP + (size_t)grow * N_NEUR + bn * 128 + pc0;
#pragma unroll
        for (int j = 0; j < 4; j++) {
            u16x8 xr8 = *(const u16x8*)&LDS[lrow * 136 + pc0 + j * 8];
            u16x8 sv8 = sv_pre[p][j];
            u16x8 o;
#pragma unroll
            for (int q = 0; q < 8; q++) {
                float xf = bf2f(xr8[q]);
                float raw = bf2f(sv8[q]) - tl;
                float sig = 1.0f / (1.0f + __expf(-raw * il));
                bool g = raw > 0.0f;
                wsum += sig * xf * xf;
                cnt += g ? 1.0f : 0.0f;
                o[q] = g ? xr8[q] : (u16)0;
            }
            *(u16x8*)(gptr + j * 8) = o;
        }
        wsum += __shfl_xor(wsum, 1);
        cnt += __shfl_xor(cnt, 1);
        wsum += __shfl_xor(wsum, 2);
        cnt += __shfl_xor(cnt, 2);
        if ((lane & 3) == 0) {
            atomicAdd(&twc[grow], wsum);
            atomicAdd(&act[grow], cnt);
        }
    }
}

// ---------------- flow A: all-chunk write GEMM -> bf16 partials --------------
__global__ __launch_bounds__(256) void k_pass2b_all(const u16* __restrict__ sbP,
                                                    const u16* __restrict__ wwT,
                                                    u16* __restrict__ part) {
    int bm = blockIdx.x;
    int bn = blockIdx.y;
    int zz = blockIdx.z;
    const u16* Pz = sbP + (size_t)zz * CS;
    const u16* Wz = wwT + (size_t)zz * CS;
    u16* pz = part + (size_t)zz * M_TOT * D_DIM;
    GEMM128_BODY(Pz, N_NEUR, Wz, N_NEUR, CS)
    RESTAGE_U16_TILE(f2bf(acc[m][n][rr]), pz, D_DIM, bn * 128)
}

// ---------------- final: sum bf16 partials, normalize, per-row outputs -------
__global__ __launch_bounds__(256) void k_norm_comb(const u16* __restrict__ part,
                                                   const float* __restrict__ twc,
                                                   const float* __restrict__ act,
                                                   float* __restrict__ out0,
                                                   float* out1, float* out2) {
    int row = blockIdx.x;
    float den = sqrtf(twc[row] + 1e-6f);
    den = fmaxf(den, 0.001f);
    float inv = 1.0f / den;
    size_t base = (size_t)row * D_DIM + threadIdx.x * 4;
    float s0 = 0.f, s1 = 0.f, s2 = 0.f, s3 = 0.f;
#pragma unroll
    for (int c = 0; c < NCHUNK; c++) {
        u16x4 v = *(const u16x4*)(part + (size_t)c * M_TOT * D_DIM + base);
        s0 += bf2f(v[0]);
        s1 += bf2f(v[1]);
        s2 += bf2f(v[2]);
        s3 += bf2f(v[3]);
    }
    float4 o;
    o.x = bf2f(f2bf(s0 * inv));
    o.y = bf2f(f2bf(s1 * inv));
    o.z = bf2f(f2bf(s2 * inv));
    o.w = bf2f(f2bf(s3 * inv));
    *(float4*)(out0 + base) = o;
    if (threadIdx.x == 0) {
        out1[row] = act[row] * (1.0f / 32768.0f);
        out2[row] = act[row] > 0.0f ? 1.0f : 0.0f;
    }
}

// ---------------- flow B kernels (compact fallback) ---------------------------
__global__ __launch_bounds__(256) void k_xr_plain(const u16* __restrict__ xb,
                                                  const u16* __restrict__ rbf,
                                                  u16* __restrict__ P) {
    int bm = blockIdx.x, bn = blockIdx.y;
    GEMM128_BODY(xb, D_DIM, rbf, D_DIM, D_DIM)
    RESTAGE_U16_TILE(f2bf(acc[m][n][rr]), P, CS, bn * 128)
}

__global__ __launch_bounds__(256) void k_gate_gemm(const u16* __restrict__ hb,
                                                   const u16* __restrict__ ebf,
                                                   const float* __restrict__ tau,
                                                   const float* __restrict__ invstd,
                                                   u16* __restrict__ P, float* twc, float* act) {
    int bm = blockIdx.x, bn = blockIdx.y;
    GEMM128_BODY(hb, D_DIM, ebf, D_DIM, D_DIM)
#pragma unroll
    for (int m = 0; m < 4; m++) {
#pragma unroll
        for (int rr = 0; rr < 4; rr++) {
            int mg = bm * 128 + wr * 64 + m * 16 + lg * 4 + rr;
            float tl = tau[mg], il = invstd[mg];
            float wsum = 0.f, cnt = 0.f;
#pragma unroll
            for (int n = 0; n < 4; n++) {
                int ngl = bn * 128 + wc * 64 + n * 16 + l15;
                float sv = bf2f(f2bf(acc[m][n][rr]));
                float raw = sv - tl;
                u16 xrb = P[(size_t)mg * CS + ngl];
                float xf = bf2f(xrb);
                float sig = 1.0f / (1.0f + __expf(-raw * il));
                bool g = raw > 0.0f;
                wsum += sig * xf * xf;
                cnt += g ? 1.0f : 0.0f;
                P[(size_t)mg * CS + ngl] = g ? xrb : (u16)0;
            }
#pragma unroll
            for (int x = 1; x < 16; x <<= 1) {
                wsum += __shfl_xor(wsum, x);
                cnt += __shfl_xor(cnt, x);
            }
            if (l15 == 0) {
                atomicAdd(&twc[mg], wsum);
                atomicAdd(&act[mg], cnt);
            }
        }
    }
}

__global__ __launch_bounds__(256) void k_pass2b(const u16* __restrict__ P,
                                                const u16* __restrict__ wwT, int bstr,
                                                float* __restrict__ out) {
    int bm = blockIdx.x;
    int bn = blockIdx.y;
    GEMM128_BODY(P, CS, wwT, bstr, CS)
#pragma unroll
    for (int m = 0; m < 4; m++)
#pragma unroll
        for (int n = 0; n < 4; n++)
#pragma unroll
            for (int rr = 0; rr < 4; rr++) {
                int mg = bm * 128 + wr * 64 + m * 16 + lg * 4 + rr;
                int dg = bn * 128 + wc * 64 + n * 16 + l15;
                out[(size_t)mg * D_DIM + dg] += bf2f(f2bf(acc[m][n][rr]));
            }
}

__global__ __launch_bounds__(256) void k_norm_f(float* __restrict__ out,
                                                const float* __restrict__ twc,
                                                const float* __restrict__ act,
                                                float* out1, float* out2) {
    int row = blockIdx.x;
    float den = sqrtf(twc[row] + 1e-6f);
    den = fmaxf(den, 0.001f);
    float inv = 1.0f / den;
    float* p = out + (size_t)row * D_DIM;
    int i = threadIdx.x * 4;
    float4 v = *(float4*)(p + i);
    v.x = bf2f(f2bf(v.x * inv));
    v.y = bf2f(f2bf(v.y * inv));
    v.z = bf2f(f2bf(v.z * inv));
    v.w = bf2f(f2bf(v.w * inv));
    *(float4*)(p + i) = v;
    if (threadIdx.x == 0) {
        out1[row] = act[row] * (1.0f / 32768.0f);
        out2[row] = act[row] > 0.0f ? 1.0f : 0.0f;
    }
}

// ---------------- scalar outputs ---------------------------------------------
__global__ __launch_bounds__(256) void k_scalars(const float* __restrict__ smean,
                                                 const float* __restrict__ sstd,
                                                 const float* __restrict__ twc,
                                                 const float* __restrict__ act,
                                                 const float* __restrict__ scal,
                                                 float* outS) {
    float a = 0.f, b = 0.f, c = 0.f, d = 0.f;
    for (int i = threadIdx.x; i < 4096; i += 256) {
        a += smean[i];
        b += sstd[i];
        c += twc[i];
        d += act[i];
    }
#pragma unroll
    for (int x = 1; x < 64; x <<= 1) {
        a += __shfl_xor(a, x);
        b += __shfl_xor(b, x);
        c += __shfl_xor(c, x);
        d += __shfl_xor(d, x);
    }
    __shared__ float sh[4][4];
    int w = threadIdx.x >> 6;
    if ((threadIdx.x & 63) == 0) { sh[0][w] = a; sh[1][w] = b; sh[2][w] = c; sh[3][w] = d; }
    __syncthreads();
    if (threadIdx.x == 0) {
        float ma = sh[0][0] + sh[0][1] + sh[0][2] + sh[0][3];
        float mb = sh[1][0] + sh[1][1] + sh[1][2] + sh[1][3];
        float mc = sh[2][0] + sh[2][1] + sh[2][2] + sh[2][3];
        float md = sh[3][0] + sh[3][1] + sh[3][2] + sh[3][3];
        float mean_score = scal[0] * (1.0f / 32768.0f);
        float var_score = scal[1] * (1.0f / 32768.0f) - mean_score * mean_score;
        outS[0] = var_score / (mean_score * mean_score + var_score + 0.01f);  // score_lb
        outS[1] = mb * (1.0f / 4096.0f);                                      // score_std_out
        outS[2] = mc * (1.0f / 4096.0f);                                      // es_out
        outS[3] = md * (1.0f / 4096.0f);                                      // active_n_mean
        outS[4] = ma * (1.0f / 4096.0f);                                      // score_mean_out
    }
}

// ---------------- workspace layout (bytes) -----------------------------------
static constexpr size_t OFF_HB     = 0;           // 8 MB
static constexpr size_t OFF_XB     = 8388608;     // 8 MB
static constexpr size_t OFF_P      = 16777216;    // 32 MB (fallback only)
static constexpr size_t OFF_EBF    = 50331648;    // 64 MB; part (64 MB bf16) overlays
static constexpr size_t OFF_RBF    = 117440512;   // 64 MB
static constexpr size_t OFF_WWT    = 184549376;   // 64 MB  [D][N] (flow A) / [D][CS] fallback
static constexpr size_t OFF_SW     = 251658240;   // 128 KB
static constexpr size_t OFF_ROWSUM = 251789312;
static constexpr size_t OFF_ROWSQ  = 251805696;
static constexpr size_t OFF_COLSUM = 251822080;   // 128 KB
static constexpr size_t OFF_TAU    = 251953152;
static constexpr size_t OFF_INVSTD = 251969536;
static constexpr size_t OFF_SMEAN  = 251985920;
static constexpr size_t OFF_SSTD   = 252002304;
static constexpr size_t OFF_TWC    = 252018688;
static constexpr size_t OFF_ACT    = 252035072;
static constexpr size_t OFF_SCAL   = 252051456;
static constexpr size_t STATS_END  = 252051520;
static constexpr size_t ZERO_LEN   = STATS_END - OFF_ROWSUM;
static constexpr size_t OFF_SB     = 252706816;   // 256 MB (flow A) scores -> gated P
static constexpr size_t FULL_END   = OFF_SB + (size_t)M_TOT * N_NEUR * 2;  // ~497 MB
static constexpr size_t OFF_PART   = OFF_EBF;     // 64 MB bf16 partials overlay

extern "C" void kernel_launch(void* const* d_in, const int* in_sizes, int n_in,
                              void* d_out, int out_size, void* d_ws, size_t ws_size,
                              hipStream_t stream) {
    const float* x = (const float*)d_in[0];
    const float* h = (const float*)d_in[1];
    const float* emb = (const float*)d_in[2];
    const float* tau_off = (const float*)d_in[3];
    const float* w_read = (const float*)d_in[4];
    const float* w_write = (const float*)d_in[5];
    char* ws = (char*)d_ws;
    u16* hb = (u16*)(ws + OFF_HB);
    u16* xb = (u16*)(ws + OFF_XB);
    u16* P = (u16*)(ws + OFF_P);
    u16* ebf = (u16*)(ws + OFF_EBF);
    u16* rbf = (u16*)(ws + OFF_RBF);
    u16* wwT = (u16*)(ws + OFF_WWT);
    float* sw = (float*)(ws + OFF_SW);
    float* rowsum = (float*)(ws + OFF_ROWSUM);
    float* rowsq = (float*)(ws + OFF_ROWSQ);
    float* colsum = (float*)(ws + OFF_COLSUM);
    float* tau = (float*)(ws + OFF_TAU);
    float* invstd = (float*)(ws + OFF_INVSTD);
    float* smean = (float*)(ws + OFF_SMEAN);
    float* sstd = (float*)(ws + OFF_SSTD);
    float* twc = (float*)(ws + OFF_TWC);
    float* act = (float*)(ws + OFF_ACT);
    float* scal = (float*)(ws + OFF_SCAL);
    u16* part = (u16*)(ws + OFF_PART);
    const bool fullA = ws_size >= FULL_END;
    u16* sbP = fullA ? (u16*)(ws + OFF_SB) : (u16*)nullptr;

    float* out0 = (float*)d_out;
    float* out1 = out0 + (size_t)M_TOT * D_DIM;
    float* out2 = out1 + M_TOT;
    float* outS = out2 + M_TOT;

    hipMemsetAsync(ws + OFF_ROWSUM, 0, ZERO_LEN, stream);

    k_cvt<<<4096, 256, 0, stream>>>(h, x, hb, xb);

    if (fullA) {
        k_cvt_ern3<<<dim3(N_NEUR / 4, 3), 256, 0, stream>>>(emb, w_read, w_write,
                                                            ebf, rbf, sw);
        k_tww<<<dim3(N_NEUR / 64, 16), 256, 0, stream>>>(w_write, sw, 0, wwT, N_NEUR);
        k_pass1<<<dim3(32, 256), 256, 0, stream>>>(hb, ebf, 0, rowsum, rowsq, colsum,
                                                   sbP, N_NEUR);
        k_ns<<<128, 256, 0, stream>>>(colsum, scal);
        k_tau<<<16, 256, 0, stream>>>(rowsum, rowsq, tau_off, tau, invstd, smean, sstd);
        k_xr_gate_all<<<dim3(32, 256), 256, 0, stream>>>(xb, rbf, sbP, tau, invstd, twc, act);
        k_pass2b_all<<<dim3(32, 8, 8), 256, 0, stream>>>(sbP, wwT, part);
        k_norm_comb<<<4096, 256, 0, stream>>>(part, twc, act, out0, out1, out2);
    } else {
        hipMemsetAsync(d_out, 0, (size_t)M_TOT * D_DIM * 4, stream);
        k_sw<<<N_NEUR / 4, 256, 0, stream>>>(w_write, sw);
        for (int c = 0; c < NCHUNK; c++) {
            k_cvt_e_norm<<<CS / 4, 256, 0, stream>>>(emb, c * CS, ebf);
            k_pass1<<<dim3(32, 32), 256, 0, stream>>>(hb, ebf, c * CS, rowsum, rowsq, colsum,
                                                      (u16*)nullptr, 0);
        }
        k_ns<<<128, 256, 0, stream>>>(colsum, scal);
        k_tau<<<16, 256, 0, stream>>>(rowsum, rowsq, tau_off, tau, invstd, smean, sstd);
        for (int c = 0; c < NCHUNK; c++) {
            k_cvt_e_norm<<<CS / 4, 256, 0, stream>>>(emb, c * CS, ebf);
            k_cvt_r_norm<<<CS / 4, 256, 0, stream>>>(w_read, c * CS, rbf);
            k_tww<<<dim3(CS / 64, 16), 256, 0, stream>>>(w_write, sw, c * CS, wwT, CS);
            k_xr_plain<<<dim3(32, 32), 256, 0, stream>>>(xb, rbf, P);
            k_gate_gemm<<<dim3(32, 32), 256, 0, stream>>>(hb, ebf, tau, invstd, P, twc, act);
            k_pass2b<<<dim3(32, 8), 256, 0, stream>>>(P, wwT, CS, out0);
        }
        k_norm_f<<<4096, 256, 0, stream>>>(out0, twc, act, out1, out2);
    }
    k_scalars<<<1, 256, 0, stream>>>(smean, sstd, twc, act, scal, outS);
}

// Round 18
// 1390.380 us; speedup vs baseline: 1.3303x; 1.0086x over previous
//
#include <hip/hip_runtime.h>
#include <stdint.h>

// Problem constants (B=4,S=1024,D=1024,N=32768,n_chunks=8)
#define M_TOT 4096
#define D_DIM 1024
#define N_NEUR 32768
#define NCHUNK 8
#define CS 4096

typedef float f32x4 __attribute__((ext_vector_type(4)));
typedef __bf16 bf16x8 __attribute__((ext_vector_type(8)));
typedef unsigned short u16;
typedef unsigned int u32;
typedef u16 u16x8 __attribute__((ext_vector_type(8)));
typedef u16 u16x4 __attribute__((ext_vector_type(4)));

__device__ __forceinline__ u16 f2bf(float f) {
    u32 u = __builtin_bit_cast(u32, f);
    u = (u + 0x7FFFu + ((u >> 16) & 1u)) >> 16;
    return (u16)u;
}
__device__ __forceinline__ float bf2f(u16 h) {
    u32 u = ((u32)h) << 16;
    return __builtin_bit_cast(float, u);
}
__device__ __forceinline__ u32 pack2(float a, float b, float s) {
    return (u32)f2bf(a * s) | ((u32)f2bf(b * s) << 16);
}

typedef __attribute__((address_space(1))) const u32 as1_u32;
typedef __attribute__((address_space(3))) u32 as3_u32;
__device__ __forceinline__ void gload16(const void* g, void* l) {
    __builtin_amdgcn_global_load_lds((as1_u32*)g, (as3_u32*)l, 16, 0, 0);
}

#define MFMA(a, b, c) __builtin_amdgcn_mfma_f32_16x16x32_bf16((a), (b), (c), 0, 0, 0)

// 128x128-tile bf16 GEMM main loop, depth-3 pipelined (T4 counted vmcnt):
// triple-buffered LDS; at iter i issue tile i+2's 4 global_load_lds, then
// s_waitcnt vmcnt(8) (tiles i+1,i+2 stay in flight; tile i proven complete),
// raw s_barrier, ds_read+MFMA on buf[i%3], s_barrier. Tail: vmcnt(4), vmcnt(0).
// Verified R16 (depth-2, -8%) and R17 (depth-3, -5%); barrier invariant:
// buffer written at iter i is buf[(i-1)%3], whose readers all passed iter
// i-1's closing barrier.
// LDS[24576] u16 (48 KB): buf k at [k*8192, +8192) = A|B halves.
// Epilogue restage reuses [0,17408) as 128 rows x stride 136.
// (R13: BK=64 regressed. R14: XCD bn-swizzle regressed. Keep BK=32, linear.)
#define GEMM128_BODY(ABASE, ASTR, BBASE, BSTR, KLEN)                                  \
    __shared__ u16 LDS[24576];                                                        \
    const int t = threadIdx.x, lane = t & 63, w = t >> 6;                             \
    const int wr = w >> 1, wc = w & 1, l15 = lane & 15, lg = lane >> 4;               \
    f32x4 acc[4][4] = {};                                                             \
    {                                                                                 \
        const int seg0 = w * 2;                                                       \
        const int rb = lane >> 2, cl = (lane & 3) * 8;                                \
        const size_t ro0 = (size_t)(seg0 * 16 + rb);                                  \
        const u16* pa0 = (ABASE) + ((size_t)bm * 128 + ro0) * (ASTR) + cl;            \
        const u16* pb0 = (BBASE) + ((size_t)bn * 128 + ro0) * (BSTR) + cl;            \
        const u16* pa1 = pa0 + (size_t)16 * (ASTR);                                   \
        const u16* pb1 = pb0 + (size_t)16 * (BSTR);                                   \
        gload16(pa0, LDS + seg0 * 512);                                               \
        gload16(pa1, LDS + seg0 * 512 + 512);                                         \
        gload16(pb0, LDS + 4096 + seg0 * 512);                                        \
        gload16(pb1, LDS + 4096 + seg0 * 512 + 512);                                  \
        if (32 < (KLEN)) {                                                            \
            gload16(pa0 + 32, LDS + 8192 + seg0 * 512);                               \
            gload16(pa1 + 32, LDS + 8192 + seg0 * 512 + 512);                         \
            gload16(pb0 + 32, LDS + 12288 + seg0 * 512);                              \
            gload16(pb1 + 32, LDS + 12288 + seg0 * 512 + 512);                        \
        }                                                                             \
        int co = 0, no = 16384;                                                       \
        for (int k0 = 0; k0 < (KLEN); k0 += 32) {                                     \
            if (k0 + 64 < (KLEN)) {                                                   \
                gload16(pa0 + k0 + 64, LDS + no + seg0 * 512);                        \
                gload16(pa1 + k0 + 64, LDS + no + seg0 * 512 + 512);                  \
                gload16(pb0 + k0 + 64, LDS + no + 4096 + seg0 * 512);                 \
                gload16(pb1 + k0 + 64, LDS + no + 4096 + seg0 * 512 + 512);           \
                asm volatile("s_waitcnt vmcnt(8)" ::: "memory");                      \
            } else if (k0 + 32 < (KLEN)) {                                            \
                asm volatile("s_waitcnt vmcnt(4)" ::: "memory");                      \
            } else {                                                                  \
                asm volatile("s_waitcnt vmcnt(0)" ::: "memory");                      \
            }                                                                         \
            __builtin_amdgcn_s_barrier();                                             \
            bf16x8 afr[4], bfr[4];                                                    \
            _Pragma("unroll") for (int m = 0; m < 4; m++)                             \
                afr[m] = *(const bf16x8*)&LDS[co + (wr * 64 + m * 16 + l15) * 32 +    \
                                              lg * 8];                                \
            _Pragma("unroll") for (int n = 0; n < 4; n++)                             \
                bfr[n] = *(const bf16x8*)&LDS[co + 4096 +                             \
                                              (wc * 64 + n * 16 + l15) * 32 + lg * 8];\
            _Pragma("unroll") for (int m = 0; m < 4; m++)                             \
                _Pragma("unroll") for (int n = 0; n < 4; n++)                         \
                    acc[m][n] = MFMA(afr[m], bfr[n], acc[m][n]);                      \
            __builtin_amdgcn_s_barrier();                                             \
            co += 8192;                                                               \
            if (co == 24576) co = 0;                                                  \
            no += 8192;                                                               \
            if (no == 24576) no = 0;                                                  \
        }                                                                             \
    }

// Single-pass full-tile restage: fragments -> LDS[128 rows][stride 136].
#define RESTAGE_TO_LDS(VALS)                                                          \
    __syncthreads();                                                                  \
    _Pragma("unroll") for (int m = 0; m < 4; m++)                                     \
        _Pragma("unroll") for (int rr = 0; rr < 4; rr++)                              \
            _Pragma("unroll") for (int n = 0; n < 4; n++) {                           \
                int lrow = wr * 64 + m * 16 + lg * 4 + rr;                            \
                LDS[lrow * 136 + wc * 64 + n * 16 + l15] = (VALS);                    \
            }                                                                         \
    __syncthreads();

// Full-tile row-major u16 writeout via the single restage (two read passes).
#define RESTAGE_U16_TILE(VALS, DSTBASE, DSTSTRIDE, COLBASE)                           \
    {                                                                                 \
        RESTAGE_TO_LDS(VALS)                                                          \
        int row_ = t >> 2, c0_ = (t & 3) * 32;                                        \
        _Pragma("unroll") for (int p = 0; p < 2; p++) {                               \
            int lrow = p * 64 + row_;                                                 \
            u16* dst_ = (DSTBASE) + (size_t)(bm * 128 + lrow) * (DSTSTRIDE) +         \
                        (COLBASE) + c0_;                                              \
            const u16* srcl_ = &LDS[lrow * 136 + c0_];                                \
            _Pragma("unroll") for (int j = 0; j < 4; j++)                             \
                *(u16x8*)(dst_ + j * 8) = *(const u16x8*)(srcl_ + j * 8);             \
        }                                                                             \
    }

// ---------------- prep: h,x -> bf16 ----------------------------------------
__global__ __launch_bounds__(256) void k_cvt(const float* __restrict__ h,
                                             const float* __restrict__ x,
                                             u16* __restrict__ hb, u16* __restrict__ xb) {
    size_t i = ((size_t)blockIdx.x * 256 + threadIdx.x) * 4;
    float4 v = *(const float4*)(h + i);
    uint2 o;
    o.x = pack2(v.x, v.y, 1.0f);
    o.y = pack2(v.z, v.w, 1.0f);
    *(uint2*)(hb + i) = o;
    v = *(const float4*)(x + i);
    o.x = pack2(v.x, v.y, 1.0f);
    o.y = pack2(v.z, v.w, 1.0f);
    *(uint2*)(xb + i) = o;
}

// ---------------- fused norm+convert: y=0 emb->ebf, y=1 w_read->rbf, y=2 sw --
__global__ __launch_bounds__(256) void k_cvt_ern3(const float* __restrict__ emb,
                                                  const float* __restrict__ wrd,
                                                  const float* __restrict__ ww,
                                                  u16* __restrict__ ebf, u16* __restrict__ rbf,
                                                  float* __restrict__ sw) {
    int t = threadIdx.x, lane = t & 63, wv = t >> 6;
    int row = blockIdx.x * 4 + wv;
    int which = blockIdx.y;
    const float* srcm = which == 0 ? emb : (which == 1 ? wrd : ww);
    const float4* src = (const float4*)(srcm + (size_t)row * D_DIM);
    float4 v[4];
    float ss = 0.f;
#pragma unroll
    for (int j = 0; j < 4; j++) {
        v[j] = src[j * 64 + lane];
        if (which == 0) {
            ss += v[j].x * v[j].x + v[j].y * v[j].y + v[j].z * v[j].z + v[j].w * v[j].w;
        } else {
            float a = bf2f(f2bf(v[j].x)), b = bf2f(f2bf(v[j].y));
            float c = bf2f(f2bf(v[j].z)), d = bf2f(f2bf(v[j].w));
            ss += a * a + b * b + c * c + d * d;
        }
    }
#pragma unroll
    for (int s = 1; s < 64; s <<= 1) ss += __shfl_xor(ss, s);
    float sc = 1.0f / (sqrtf(ss) + 1e-8f);
    if (which == 2) {
        if (lane == 0) sw[row] = sc;
        return;
    }
    uint2* dst = (uint2*)((which == 0 ? ebf : rbf) + (size_t)row * D_DIM);
#pragma unroll
    for (int j = 0; j < 4; j++) {
        uint2 o;
        o.x = pack2(v[j].x, v[j].y, sc);
        o.y = pack2(v[j].z, v[j].w, sc);
        dst[j * 64 + lane] = o;
    }
}

// per-chunk variants for the compact fallback path
__global__ __launch_bounds__(256) void k_cvt_e_norm(const float* __restrict__ emb,
                                                    int cbase, u16* __restrict__ ebf) {
    int t = threadIdx.x, lane = t & 63, wv = t >> 6;
    int row = blockIdx.x * 4 + wv;
    const float4* src = (const float4*)(emb + (size_t)(cbase + row) * D_DIM);
    float4 v[4];
    float ss = 0.f;
#pragma unroll
    for (int j = 0; j < 4; j++) {
        v[j] = src[j * 64 + lane];
        ss += v[j].x * v[j].x + v[j].y * v[j].y + v[j].z * v[j].z + v[j].w * v[j].w;
    }
#pragma unroll
    for (int s = 1; s < 64; s <<= 1) ss += __shfl_xor(ss, s);
    float es = 1.0f / (sqrtf(ss) + 1e-8f);
    uint2* dst = (uint2*)(ebf + (size_t)row * D_DIM);
#pragma unroll
    for (int j = 0; j < 4; j++) {
        uint2 o;
        o.x = pack2(v[j].x, v[j].y, es);
        o.y = pack2(v[j].z, v[j].w, es);
        dst[j * 64 + lane] = o;
    }
}

__global__ __launch_bounds__(256) void k_cvt_r_norm(const float* __restrict__ wrd,
                                                    int cbase, u16* __restrict__ rbf) {
    int t = threadIdx.x, lane = t & 63, wv = t >> 6;
    int row = blockIdx.x * 4 + wv;
    const float4* src = (const float4*)(wrd + (size_t)(cbase + row) * D_DIM);
    float4 v[4];
    float ss = 0.f;
#pragma unroll
    for (int j = 0; j < 4; j++) {
        v[j] = src[j * 64 + lane];
        float a = bf2f(f2bf(v[j].x)), b = bf2f(f2bf(v[j].y));
        float c = bf2f(f2bf(v[j].z)), d = bf2f(f2bf(v[j].w));
        ss += a * a + b * b + c * c + d * d;
    }
#pragma unroll
    for (int s = 1; s < 64; s <<= 1) ss += __shfl_xor(ss, s);
    float rs = 1.0f / (sqrtf(ss) + 1e-8f);
    uint2* dst = (uint2*)(rbf + (size_t)row * D_DIM);
#pragma unroll
    for (int j = 0; j < 4; j++) {
        uint2 o;
        o.x = pack2(v[j].x, v[j].y, rs);
        o.y = pack2(v[j].z, v[j].w, rs);
        dst[j * 64 + lane] = o;
    }
}

// ---------------- w_write row norms (fallback path) ---------------------------
__global__ __launch_bounds__(256) void k_sw(const float* __restrict__ ww, float* sw) {
    int t = threadIdx.x, lane = t & 63, wv = t >> 6;
    int row = blockIdx.x * 4 + wv;
    const float4* src = (const float4*)(ww + (size_t)row * D_DIM);
    float ss = 0.f;
#pragma unroll
    for (int j = 0; j < 4; j++) {
        float4 v = src[j * 64 + lane];
        float a = bf2f(f2bf(v.x)), b = bf2f(f2bf(v.y));
        float c = bf2f(f2bf(v.z)), d = bf2f(f2bf(v.w));
        ss += a * a + b * b + c * c + d * d;
    }
#pragma unroll
    for (int s = 1; s < 64; s <<= 1) ss += __shfl_xor(ss, s);
    if (lane == 0) sw[row] = 1.0f / (sqrtf(ss) + 1e-8f);
}

// ---------------- transpose w_write -> wwT[d][k] bf16 ------------------------
__global__ __launch_bounds__(256) void k_tww(const float* __restrict__ ww,
                                             const float* __restrict__ sw,
                                             int cbase, u16* __restrict__ wwT, int dstr) {
    __shared__ u16 tile[64][80];
    int kt = blockIdx.x * 64;
    int dt = blockIdx.y * 64;
    int t = threadIdx.x;
    int kk = t >> 4;
    int dd = (t & 15) * 4;
#pragma unroll
    for (int i = 0; i < 4; i++) {
        int krow = kk + i * 16;
        int kg = cbase + kt + krow;
        float s = sw[kg];
        float4 v = *(const float4*)(ww + (size_t)kg * D_DIM + dt + dd);
        tile[dd + 0][krow] = f2bf(v.x * s);
        tile[dd + 1][krow] = f2bf(v.y * s);
        tile[dd + 2][krow] = f2bf(v.z * s);
        tile[dd + 3][krow] = f2bf(v.w * s);
    }
    __syncthreads();
    int dd2 = t >> 2;
    int kk2 = (t & 3) * 16;
    uint4 o0 = *(const uint4*)&tile[dd2][kk2];
    uint4 o1 = *(const uint4*)&tile[dd2][kk2 + 8];
    u16* dst = wwT + (size_t)(dt + dd2) * dstr + kt + kk2;
    *(uint4*)dst = o0;
    *(uint4*)(dst + 8) = o1;
}

// ---------------- pass 1: scores GEMM + stats + row-major sb ------------------
__global__ __launch_bounds__(256) void k_pass1(const u16* __restrict__ hb,
                                               const u16* __restrict__ ebf, int cbase,
                                               float* rowsum, float* rowsq, float* colsum,
                                               u16* __restrict__ sb, int sstr) {
    int bm = blockIdx.x, bn = blockIdx.y;
    GEMM128_BODY(hb, D_DIM, ebf, D_DIM, D_DIM)
    // column sums from fragments (bf16-rounded values)
    float csv[4] = {0.f, 0.f, 0.f, 0.f};
#pragma unroll
    for (int m = 0; m < 4; m++)
#pragma unroll
        for (int rr = 0; rr < 4; rr++)
#pragma unroll
            for (int n = 0; n < 4; n++) csv[n] += bf2f(f2bf(acc[m][n][rr]));
#pragma unroll
    for (int n = 0; n < 4; n++) {
        float cv = csv[n];
        cv += __shfl_xor(cv, 16);
        cv += __shfl_xor(cv, 32);
        if (lg == 0) {
            int ng = cbase + bn * 128 + wc * 64 + n * 16 + l15;
            atomicAdd(&colsum[ng], cv);
        }
    }
    // restage full tile once; row stats + coalesced sb store in two passes
    RESTAGE_TO_LDS(f2bf(acc[m][n][rr]))
    int row_ = t >> 2, c0_ = (t & 3) * 32;
#pragma unroll
    for (int p = 0; p < 2; p++) {
        int lrow = p * 64 + row_;
        int grow = bm * 128 + lrow;
        float rs = 0.f, rq = 0.f;
        u16* dst = sb ? (sb + (size_t)grow * sstr + cbase + bn * 128 + c0_) : (u16*)nullptr;
#pragma unroll
        for (int j = 0; j < 4; j++) {
            u16x8 v = *(const u16x8*)&LDS[lrow * 136 + c0_ + j * 8];
            if (dst) *(u16x8*)(dst + j * 8) = v;
#pragma unroll
            for (int q = 0; q < 8; q++) {
                float sv = bf2f(v[q]);
                rs += sv;
                rq += sv * sv;
            }
        }
        rs += __shfl_xor(rs, 1);
        rq += __shfl_xor(rq, 1);
        rs += __shfl_xor(rs, 2);
        rq += __shfl_xor(rq, 2);
        if ((lane & 3) == 0) {
            atomicAdd(&rowsum[grow], rs);
            atomicAdd(&rowsq[grow], rq);
        }
    }
}

// ---------------- ns stats reduce -------------------------------------------
__global__ __launch_bounds__(256) void k_ns(const float* __restrict__ colsum, float* scal) {
    int i = blockIdx.x * 256 + threadIdx.x;
    float pm = colsum[i] * (1.0f / 4096.0f);
    float s1 = pm, s2 = pm * pm;
#pragma unroll
    for (int x = 1; x < 64; x <<= 1) {
        s1 += __shfl_xor(s1, x);
        s2 += __shfl_xor(s2, x);
    }
    __shared__ float sh[2][4];
    int w = threadIdx.x >> 6;
    if ((threadIdx.x & 63) == 0) { sh[0][w] = s1; sh[1][w] = s2; }
    __syncthreads();
    if (threadIdx.x == 0) {
        atomicAdd(&scal[0], sh[0][0] + sh[0][1] + sh[0][2] + sh[0][3]);
        atomicAdd(&scal[1], sh[1][0] + sh[1][1] + sh[1][2] + sh[1][3]);
    }
}

// ---------------- tau --------------------------------------------------------
__global__ __launch_bounds__(256) void k_tau(const float* __restrict__ rowsum,
                                             const float* __restrict__ rowsq,
                                             const float* __restrict__ tau_off,
                                             float* tau, float* invstd, float* smean, float* sstd) {
    int i = blockIdx.x * 256 + threadIdx.x;
    float sm = rowsum[i] * (1.0f / 32768.0f);
    float var = rowsq[i] * (1.0f / 32768.0f) - sm * sm;
    float sd = sqrtf(var) + 1e-8f;
    smean[i] = sm;
    sstd[i] = sd;
    invstd[i] = 1.0f / sd;
    tau[i] = sm + tau_off[i] * sd;
}

// ---------------- flow A: xr GEMM + gate, P in-place into sb ------------------
// sv loads issued AFTER the K-loop, just before the restage: the restage's
// two barriers + 128 LDS writes cover the load latency, and the 32 VGPRs of
// sv state are no longer live across the GEMM (occupancy-quantum experiment:
// target <=128 total regs -> 4 waves/SIMD per m69's allocation steps).
__global__ __launch_bounds__(256) void k_xr_gate_all(const u16* __restrict__ xb,
                                                     const u16* __restrict__ rbf,
                                                     u16* __restrict__ sbP,
                                                     const float* __restrict__ tau,
                                                     const float* __restrict__ invstd,
                                                     float* twc, float* act) {
    int bm = blockIdx.x, bn = blockIdx.y;
    GEMM128_BODY(xb, D_DIM, rbf, D_DIM, D_DIM)
    const int prow = t >> 2, pc0 = (t & 3) * 32;
    // issue sv loads; restage below covers their latency
    u16x8 sv_pre[2][4];
#pragma unroll
    for (int p = 0; p < 2; p++) {
        int grow = bm * 128 + p * 64 + prow;
        const u16* src = sbP + (size_t)grow * N_NEUR + bn * 128 + pc0;
#pragma unroll
        for (int j = 0; j < 4; j++) sv_pre[p][j] = *(const u16x8*)(src + j * 8);
    }
    RESTAGE_TO_LDS(f2bf(acc[m][n][rr]))
#pragma unroll
    for (int p = 0; p < 2; p++) {
        int lrow = p * 64 + prow;
        int grow = bm * 128 + lrow;
        float tl = tau[grow], il = invstd[grow];
        float wsum = 0.f, cnt = 0.f;
        u16* gptr = sbP + (size_t)grow * N_NEUR + bn * 128 + pc0;
#pragma unroll
        for (int j = 0; j < 4; j++) {
            u16x8 xr8 = *(const u16x8*)&LDS[lrow * 136 + pc0 + j * 8];
            u16x8 sv8 = sv_pre[p][j];
            u16x8 o;
#pragma unroll
            for (int q = 0; q < 8; q++) {
                float xf = bf2f(xr8[q]);
                float raw = bf2f(sv8[q]) - tl;
                float sig = 1.0f / (1.0f + __expf(-raw * il));
                bool g = raw > 0.0f;
                wsum += sig * xf * xf;
                cnt += g ? 1.0f : 0.0f;
                o[q] = g ? xr8[q] : (u16)0;
            }
            *(u16x8*)(gptr + j * 8) = o;
        }
        wsum += __shfl_xor(wsum, 1);
        cnt += __shfl_xor(cnt, 1);
        wsum += __shfl_xor(wsum, 2);
        cnt += __shfl_xor(cnt, 2);
        if ((lane & 3) == 0) {
            atomicAdd(&twc[grow], wsum);
            atomicAdd(&act[grow], cnt);
        }
    }
}

// ---------------- flow A: all-chunk write GEMM -> bf16 partials --------------
__global__ __launch_bounds__(256) void k_pass2b_all(const u16* __restrict__ sbP,
                                                    const u16* __restrict__ wwT,
                                                    u16* __restrict__ part) {
    int bm = blockIdx.x;
    int bn = blockIdx.y;
    int zz = blockIdx.z;
    const u16* Pz = sbP + (size_t)zz * CS;
    const u16* Wz = wwT + (size_t)zz * CS;
    u16* pz = part + (size_t)zz * M_TOT * D_DIM;
    GEMM128_BODY(Pz, N_NEUR, Wz, N_NEUR, CS)
    RESTAGE_U16_TILE(f2bf(acc[m][n][rr]), pz, D_DIM, bn * 128)
}

// ---------------- final: sum bf16 partials, normalize, per-row outputs -------
__global__ __launch_bounds__(256) void k_norm_comb(const u16* __restrict__ part,
                                                   const float* __restrict__ twc,
                                                   const float* __restrict__ act,
                                                   float* __restrict__ out0,
                                                   float* out1, float* out2) {
    int row = blockIdx.x;
    float den = sqrtf(twc[row] + 1e-6f);
    den = fmaxf(den, 0.001f);
    float inv = 1.0f / den;
    size_t base = (size_t)row * D_DIM + threadIdx.x * 4;
    float s0 = 0.f, s1 = 0.f, s2 = 0.f, s3 = 0.f;
#pragma unroll
    for (int c = 0; c < NCHUNK; c++) {
        u16x4 v = *(const u16x4*)(part + (size_t)c * M_TOT * D_DIM + base);
        s0 += bf2f(v[0]);
        s1 += bf2f(v[1]);
        s2 += bf2f(v[2]);
        s3 += bf2f(v[3]);
    }
    float4 o;
    o.x = bf2f(f2bf(s0 * inv));
    o.y = bf2f(f2bf(s1 * inv));
    o.z = bf2f(f2bf(s2 * inv));
    o.w = bf2f(f2bf(s3 * inv));
    *(float4*)(out0 + base) = o;
    if (threadIdx.x == 0) {
        out1[row] = act[row] * (1.0f / 32768.0f);
        out2[row] = act[row] > 0.0f ? 1.0f : 0.0f;
    }
}

// ---------------- flow B kernels (compact fallback) ---------------------------
__global__ __launch_bounds__(256) void k_xr_plain(const u16* __restrict__ xb,
                                                  const u16* __restrict__ rbf,
                                                  u16* __restrict__ P) {
    int bm = blockIdx.x, bn = blockIdx.y;
    GEMM128_BODY(xb, D_DIM, rbf, D_DIM, D_DIM)
    RESTAGE_U16_TILE(f2bf(acc[m][n][rr]), P, CS, bn * 128)
}

__global__ __launch_bounds__(256) void k_gate_gemm(const u16* __restrict__ hb,
                                                   const u16* __restrict__ ebf,
                                                   const float* __restrict__ tau,
                                                   const float* __restrict__ invstd,
                                                   u16* __restrict__ P, float* twc, float* act) {
    int bm = blockIdx.x, bn = blockIdx.y;
    GEMM128_BODY(hb, D_DIM, ebf, D_DIM, D_DIM)
#pragma unroll
    for (int m = 0; m < 4; m++) {
#pragma unroll
        for (int rr = 0; rr < 4; rr++) {
            int mg = bm * 128 + wr * 64 + m * 16 + lg * 4 + rr;
            float tl = tau[mg], il = invstd[mg];
            float wsum = 0.f, cnt = 0.f;
#pragma unroll
            for (int n = 0; n < 4; n++) {
                int ngl = bn * 128 + wc * 64 + n * 16 + l15;
                float sv = bf2f(f2bf(acc[m][n][rr]));
                float raw = sv - tl;
                u16 xrb = P[(size_t)mg * CS + ngl];
                float xf = bf2f(xrb);
                float sig = 1.0f / (1.0f + __expf(-raw * il));
                bool g = raw > 0.0f;
                wsum += sig * xf * xf;
                cnt += g ? 1.0f : 0.0f;
                P[(size_t)mg * CS + ngl] = g ? xrb : (u16)0;
            }
#pragma unroll
            for (int x = 1; x < 16; x <<= 1) {
                wsum += __shfl_xor(wsum, x);
                cnt += __shfl_xor(cnt, x);
            }
            if (l15 == 0) {
                atomicAdd(&twc[mg], wsum);
                atomicAdd(&act[mg], cnt);
            }
        }
    }
}

__global__ __launch_bounds__(256) void k_pass2b(const u16* __restrict__ P,
                                                const u16* __restrict__ wwT, int bstr,
                                                float* __restrict__ out) {
    int bm = blockIdx.x;
    int bn = blockIdx.y;
    GEMM128_BODY(P, CS, wwT, bstr, CS)
#pragma unroll
    for (int m = 0; m < 4; m++)
#pragma unroll
        for (int n = 0; n < 4; n++)
#pragma unroll
            for (int rr = 0; rr < 4; rr++) {
                int mg = bm * 128 + wr * 64 + m * 16 + lg * 4 + rr;
                int dg = bn * 128 + wc * 64 + n * 16 + l15;
                out[(size_t)mg * D_DIM + dg] += bf2f(f2bf(acc[m][n][rr]));
            }
}

__global__ __launch_bounds__(256) void k_norm_f(float* __restrict__ out,
                                                const float* __restrict__ twc,
                                                const float* __restrict__ act,
                                                float* out1, float* out2) {
    int row = blockIdx.x;
    float den = sqrtf(twc[row] + 1e-6f);
    den = fmaxf(den, 0.001f);
    float inv = 1.0f / den;
    float* p = out + (size_t)row * D_DIM;
    int i = threadIdx.x * 4;
    float4 v = *(float4*)(p + i);
    v.x = bf2f(f2bf(v.x * inv));
    v.y = bf2f(f2bf(v.y * inv));
    v.z = bf2f(f2bf(v.z * inv));
    v.w = bf2f(f2bf(v.w * inv));
    *(float4*)(p + i) = v;
    if (threadIdx.x == 0) {
        out1[row] = act[row] * (1.0f / 32768.0f);
        out2[row] = act[row] > 0.0f ? 1.0f : 0.0f;
    }
}

// ---------------- scalar outputs ---------------------------------------------
__global__ __launch_bounds__(256) void k_scalars(const float* __restrict__ smean,
                                                 const float* __restrict__ sstd,
                                                 const float* __restrict__ twc,
                                                 const float* __restrict__ act,
                                                 const float* __restrict__ scal,
                                                 float* outS) {
    float a = 0.f, b = 0.f, c = 0.f, d = 0.f;
    for (int i = threadIdx.x; i < 4096; i += 256) {
        a += smean[i];
        b += sstd[i];
        c += twc[i];
        d += act[i];
    }
#pragma unroll
    for (int x = 1; x < 64; x <<= 1) {
        a += __shfl_xor(a, x);
        b += __shfl_xor(b, x);
        c += __shfl_xor(c, x);
        d += __shfl_xor(d, x);
    }
    __shared__ float sh[4][4];
    int w = threadIdx.x >> 6;
    if ((threadIdx.x & 63) == 0) { sh[0][w] = a; sh[1][w] = b; sh[2][w] = c; sh[3][w] = d; }
    __syncthreads();
    if (threadIdx.x == 0) {
        float ma = sh[0][0] + sh[0][1] + sh[0][2] + sh[0][3];
        float mb = sh[1][0] + sh[1][1] + sh[1][2] + sh[1][3];
        float mc = sh[2][0] + sh[2][1] + sh[2][2] + sh[2][3];
        float md = sh[3][0] + sh[3][1] + sh[3][2] + sh[3][3];
        float mean_score = scal[0] * (1.0f / 32768.0f);
        float var_score = scal[1] * (1.0f / 32768.0f) - mean_score * mean_score;
        outS[0] = var_score / (mean_score * mean_score + var_score + 0.01f);  // score_lb
        outS[1] = mb * (1.0f / 4096.0f);                                      // score_std_out
        outS[2] = mc * (1.0f / 4096.0f);                                      // es_out
        outS[3] = md * (1.0f / 4096.0f);                                      // active_n_mean
        outS[4] = ma * (1.0f / 4096.0f);                                      // score_mean_out
    }
}

// ---------------- workspace layout (bytes) -----------------------------------
static constexpr size_t OFF_HB     = 0;           // 8 MB
static constexpr size_t OFF_XB     = 8388608;     // 8 MB
static constexpr size_t OFF_P      = 16777216;    // 32 MB (fallback only)
static constexpr size_t OFF_EBF    = 50331648;    // 64 MB; part (64 MB bf16) overlays
static constexpr size_t OFF_RBF    = 117440512;   // 64 MB
static constexpr size_t OFF_WWT    = 184549376;   // 64 MB  [D][N] (flow A) / [D][CS] fallback
static constexpr size_t OFF_SW     = 251658240;   // 128 KB
static constexpr size_t OFF_ROWSUM = 251789312;
static constexpr size_t OFF_ROWSQ  = 251805696;
static constexpr size_t OFF_COLSUM = 251822080;   // 128 KB
static constexpr size_t OFF_TAU    = 251953152;
static constexpr size_t OFF_INVSTD = 251969536;
static constexpr size_t OFF_SMEAN  = 251985920;
static constexpr size_t OFF_SSTD   = 252002304;
static constexpr size_t OFF_TWC    = 252018688;
static constexpr size_t OFF_ACT    = 252035072;
static constexpr size_t OFF_SCAL   = 252051456;
static constexpr size_t STATS_END  = 252051520;
static constexpr size_t ZERO_LEN   = STATS_END - OFF_ROWSUM;
static constexpr size_t OFF_SB     = 252706816;   // 256 MB (flow A) scores -> gated P
static constexpr size_t FULL_END   = OFF_SB + (size_t)M_TOT * N_NEUR * 2;  // ~497 MB
static constexpr size_t OFF_PART   = OFF_EBF;     // 64 MB bf16 partials overlay

extern "C" void kernel_launch(void* const* d_in, const int* in_sizes, int n_in,
                              void* d_out, int out_size, void* d_ws, size_t ws_size,
                              hipStream_t stream) {
    const float* x = (const float*)d_in[0];
    const float* h = (const float*)d_in[1];
    const float* emb = (const float*)d_in[2];
    const float* tau_off = (const float*)d_in[3];
    const float* w_read = (const float*)d_in[4];
    const float* w_write = (const float*)d_in[5];
    char* ws = (char*)d_ws;
    u16* hb = (u16*)(ws + OFF_HB);
    u16* xb = (u16*)(ws + OFF_XB);
    u16* P = (u16*)(ws + OFF_P);
    u16* ebf = (u16*)(ws + OFF_EBF);
    u16* rbf = (u16*)(ws + OFF_RBF);
    u16* wwT = (u16*)(ws + OFF_WWT);
    float* sw = (float*)(ws + OFF_SW);
    float* rowsum = (float*)(ws + OFF_ROWSUM);
    float* rowsq = (float*)(ws + OFF_ROWSQ);
    float* colsum = (float*)(ws + OFF_COLSUM);
    float* tau = (float*)(ws + OFF_TAU);
    float* invstd = (float*)(ws + OFF_INVSTD);
    float* smean = (float*)(ws + OFF_SMEAN);
    float* sstd = (float*)(ws + OFF_SSTD);
    float* twc = (float*)(ws + OFF_TWC);
    float* act = (float*)(ws + OFF_ACT);
    float* scal = (float*)(ws + OFF_SCAL);
    u16* part = (u16*)(ws + OFF_PART);
    const bool fullA = ws_size >= FULL_END;
    u16* sbP = fullA ? (u16*)(ws + OFF_SB) : (u16*)nullptr;

    float* out0 = (float*)d_out;
    float* out1 = out0 + (size_t)M_TOT * D_DIM;
    float* out2 = out1 + M_TOT;
    float* outS = out2 + M_TOT;

    hipMemsetAsync(ws + OFF_ROWSUM, 0, ZERO_LEN, stream);

    k_cvt<<<4096, 256, 0, stream>>>(h, x, hb, xb);

    if (fullA) {
        k_cvt_ern3<<<dim3(N_NEUR / 4, 3), 256, 0, stream>>>(emb, w_read, w_write,
                                                            ebf, rbf, sw);
        k_tww<<<dim3(N_NEUR / 64, 16), 256, 0, stream>>>(w_write, sw, 0, wwT, N_NEUR);
        k_pass1<<<dim3(32, 256), 256, 0, stream>>>(hb, ebf, 0, rowsum, rowsq, colsum,
                                                   sbP, N_NEUR);
        k_ns<<<128, 256, 0, stream>>>(colsum, scal);
        k_tau<<<16, 256, 0, stream>>>(rowsum, rowsq, tau_off, tau, invstd, smean, sstd);
        k_xr_gate_all<<<dim3(32, 256), 256, 0, stream>>>(xb, rbf, sbP, tau, invstd, twc, act);
        k_pass2b_all<<<dim3(32, 8, 8), 256, 0, stream>>>(sbP, wwT, part);
        k_norm_comb<<<4096, 256, 0, stream>>>(part, twc, act, out0, out1, out2);
    } else {
        hipMemsetAsync(d_out, 0, (size_t)M_TOT * D_DIM * 4, stream);
        k_sw<<<N_NEUR / 4, 256, 0, stream>>>(w_write, sw);
        for (int c = 0; c < NCHUNK; c++) {
            k_cvt_e_norm<<<CS / 4, 256, 0, stream>>>(emb, c * CS, ebf);
            k_pass1<<<dim3(32, 32), 256, 0, stream>>>(hb, ebf, c * CS, rowsum, rowsq, colsum,
                                                      (u16*)nullptr, 0);
        }
        k_ns<<<128, 256, 0, stream>>>(colsum, scal);
        k_tau<<<16, 256, 0, stream>>>(rowsum, rowsq, tau_off, tau, invstd, smean, sstd);
        for (int c = 0; c < NCHUNK; c++) {
            k_cvt_e_norm<<<CS / 4, 256, 0, stream>>>(emb, c * CS, ebf);
            k_cvt_r_norm<<<CS / 4, 256, 0, stream>>>(w_read, c * CS, rbf);
            k_tww<<<dim3(CS / 64, 16), 256, 0, stream>>>(w_write, sw, c * CS, wwT, CS);
            k_xr_plain<<<dim3(32, 32), 256, 0, stream>>>(xb, rbf, P);
            k_gate_gemm<<<dim3(32, 32), 256, 0, stream>>>(hb, ebf, tau, invstd, P, twc, act);
            k_pass2b<<<dim3(32, 8), 256, 0, stream>>>(P, wwT, CS, out0);
        }
        k_norm_f<<<4096, 256, 0, stream>>>(out0, twc, act, out1, out2);
    }
    k_scalars<<<1, 256, 0, stream>>>(smean, sstd, twc, act, scal, outS);
}